// Round 2
// baseline (10091.013 us; speedup 1.0000x reference)
//
#include <hip/hip_runtime.h>
#include <math.h>

#define NB 16384
#define ND 256
#define NH 2048
#define NOUT 255
#define CH 2048          // batch chunk rows
#define NCHUNK (NB / CH)

constexpr float C_ALPHA  = 0.01f;
constexpr float C_REHU_D = 0.01f;
constexpr float C_PSD_D  = 1.0f;
constexpr float C_EPS    = 1e-5f;

// ---- scratch in device globals (independent of ws_size) ----
__device__ float g_spU0[(size_t)NH * NH];
__device__ float g_spU1[NH];
__device__ float g_z10[NH];
__device__ float g_a20[NH];
__device__ float g_ic0[1];
__device__ float g_bufA[(size_t)CH * NH];
__device__ float g_bufB[(size_t)CH * NH];
__device__ float g_fx[(size_t)CH * ND];
__device__ float g_gV[(size_t)CH * ND];
__device__ float g_sS[CH];
__device__ float g_sVx[CH];

__device__ __forceinline__ float softplus_f(float x) {
    return fmaxf(x, 0.0f) + log1pf(expf(-fabsf(x)));
}
__device__ __forceinline__ float rehu_f(float x, float d) {
    float t = x * fabsf(x) / (2.0f * d);
    t = fminf(fmaxf(t, 0.0f), 0.5f * d);
    return fmaxf(t, x - 0.5f * d);
}
__device__ __forceinline__ float drehu_f(float x, float d) {
    return fminf(fmaxf(x / d, 0.0f), 1.0f);
}

// valid result on thread 0 only
__device__ __forceinline__ float block_reduce_sum(float v, float* sbuf) {
    #pragma unroll
    for (int off = 32; off > 0; off >>= 1) v += __shfl_down(v, off, 64);
    const int lane = threadIdx.x & 63;
    const int wid  = threadIdx.x >> 6;
    if (lane == 0) sbuf[wid] = v;
    __syncthreads();
    float r = 0.0f;
    if (wid == 0) {
        r = (lane < 4) ? sbuf[lane] : 0.0f;
        r += __shfl_down(r, 2, 64);
        r += __shfl_down(r, 1, 64);
    }
    __syncthreads();
    return r;
}

// Y[M,N](ldY) = EPI( alpha * (A' @ B') + bias + (ACC ? Y : 0) )
// A: [M,K] row-major; TRA=1 applies rehu(.,0.01) to A on load.
// TRANSB=1: Bm is [N,K] (Y = A@B^T). TRANSB=0: Bm is [K,N] (Y = A@B).
// EPI: 0 none, 1 relu, 3 multiply by drehu(aux[m,n], 0.01).
template<int TRANSB, int TRA, int EPI, int ACC, int HASBIAS>
__global__ __launch_bounds__(256) void gemm_kernel(
    float* __restrict__ Y, const float* __restrict__ A,
    const float* __restrict__ Bm, const float* __restrict__ bias,
    const float* __restrict__ aux,
    int M, int N, int K, int ldY, float alpha)
{
    __shared__ float As[16][68];
    __shared__ float Bs[16][68];
    const int tid = threadIdx.x;
    const int tx = tid & 15;
    const int ty = tid >> 4;
    const int row0 = blockIdx.y * 64;
    const int col0 = blockIdx.x * 64;

    float acc[4][4] = {};

    const int lr = tid >> 2;          // 0..63
    const int lk = (tid & 3) << 2;    // 0,4,8,12

    for (int k0 = 0; k0 < K; k0 += 16) {
        {
            float4 v = *reinterpret_cast<const float4*>(A + (size_t)(row0 + lr) * K + (k0 + lk));
            if (TRA) {
                v.x = rehu_f(v.x, C_REHU_D); v.y = rehu_f(v.y, C_REHU_D);
                v.z = rehu_f(v.z, C_REHU_D); v.w = rehu_f(v.w, C_REHU_D);
            }
            As[lk + 0][lr] = v.x; As[lk + 1][lr] = v.y;
            As[lk + 2][lr] = v.z; As[lk + 3][lr] = v.w;
        }
        if (TRANSB) {
            const int n = col0 + lr;
            float4 v = make_float4(0.f, 0.f, 0.f, 0.f);
            if (n < N) v = *reinterpret_cast<const float4*>(Bm + (size_t)n * K + (k0 + lk));
            Bs[lk + 0][lr] = v.x; Bs[lk + 1][lr] = v.y;
            Bs[lk + 2][lr] = v.z; Bs[lk + 3][lr] = v.w;
        } else {
            const int bk = tid >> 4;            // 0..15
            const int bn = (tid & 15) << 2;     // 0..60
            float4 v = *reinterpret_cast<const float4*>(Bm + (size_t)(k0 + bk) * N + (col0 + bn));
            *reinterpret_cast<float4*>(&Bs[bk][bn]) = v;
        }
        __syncthreads();
        #pragma unroll
        for (int k = 0; k < 16; ++k) {
            const float4 av = *reinterpret_cast<const float4*>(&As[k][ty << 2]);
            const float4 bv = *reinterpret_cast<const float4*>(&Bs[k][tx << 2]);
            const float a4[4] = {av.x, av.y, av.z, av.w};
            const float b4[4] = {bv.x, bv.y, bv.z, bv.w};
            #pragma unroll
            for (int i = 0; i < 4; ++i)
                #pragma unroll
                for (int j = 0; j < 4; ++j)
                    acc[i][j] = fmaf(a4[i], b4[j], acc[i][j]);
        }
        __syncthreads();
    }

    #pragma unroll
    for (int i = 0; i < 4; ++i) {
        const int r = row0 + (ty << 2) + i;
        #pragma unroll
        for (int j = 0; j < 4; ++j) {
            const int c = col0 + (tx << 2) + j;
            if (c < N) {
                float v = alpha * acc[i][j];
                if (HASBIAS) v += bias[c];
                const size_t idx = (size_t)r * ldY + c;
                if (ACC) v += Y[idx];
                if (EPI == 1) v = fmaxf(v, 0.0f);
                if (EPI == 3) v *= drehu_f(aux[idx], C_REHU_D);
                Y[idx] = v;
            }
        }
    }
}

__global__ void ew_softplus(float* __restrict__ dst, const float* __restrict__ src, long n) {
    long i = (long)blockIdx.x * blockDim.x + threadIdx.x;
    const long stride = (long)gridDim.x * blockDim.x;
    for (; i < n; i += stride) dst[i] = softplus_f(src[i]);
}

__global__ void ew_rehu(float* __restrict__ dst, const float* __restrict__ src, long n) {
    long i = (long)blockIdx.x * blockDim.x + threadIdx.x;
    const long stride = (long)gridDim.x * blockDim.x;
    for (; i < n; i += stride) dst[i] = rehu_f(src[i], C_REHU_D);
}

__global__ void set_ones_col(float* __restrict__ fx, int rows) {
    const int b = blockIdx.x * blockDim.x + threadIdx.x;
    if (b < rows) fx[(size_t)b * ND + (ND - 1)] = 1.0f;
}

// a2_0[j] = vb1[j] + (1/H) * sum_k z1_0[k] * spU0[j,k]
__global__ __launch_bounds__(256) void a20_kernel(
    float* __restrict__ a20, const float* __restrict__ z10,
    const float* __restrict__ spU0, const float* __restrict__ vb1)
{
    __shared__ float sbuf[4];
    const int j = blockIdx.x;
    float sum = 0.0f;
    const float* row = spU0 + (size_t)j * NH;
    for (int k = threadIdx.x; k < NH; k += 256) sum += z10[k] * row[k];
    sum = block_reduce_sum(sum, sbuf);
    if (threadIdx.x == 0) a20[j] = vb1[j] + sum * (1.0f / NH);
}

// icnn0 = vb2 + sum_j rehu(a2_0[j]) * spU1[j]     (divide by vU1.shape[0] == 1!)
__global__ __launch_bounds__(256) void icnn0_kernel(
    float* __restrict__ ic0, const float* __restrict__ a20,
    const float* __restrict__ spU1, const float* __restrict__ vb2)
{
    __shared__ float sbuf[4];
    float sum = 0.0f;
    for (int j = threadIdx.x; j < NH; j += 256) sum += rehu_f(a20[j], C_REHU_D) * spU1[j];
    sum = block_reduce_sum(sum, sbuf);
    if (threadIdx.x == 0) ic0[0] = vb2[0] + sum;
}

// per row: icnn_x = x.vW2 + vb2 + sum_j rehu(a2)*spU1 ; diff = icnn_x - icnn0
// s = clamp(diff,0,1) ; Vx = rehu(diff,1) + eps*||x||^2
__global__ __launch_bounds__(256) void rowstats_kernel(
    float* __restrict__ sS, float* __restrict__ sVx,
    const float* __restrict__ x, const float* __restrict__ a2,
    const float* __restrict__ spU1, const float* __restrict__ vW2,
    const float* __restrict__ vb2, const float* __restrict__ ic0)
{
    __shared__ float sbuf[4];
    const int b = blockIdx.x;
    const int t = threadIdx.x;
    const float xv = x[(size_t)b * ND + t];
    float zsum = 0.0f;
    const float* a2r = a2 + (size_t)b * NH;
    for (int j = t; j < NH; j += 256) zsum += rehu_f(a2r[j], C_REHU_D) * spU1[j];
    const float d1 = block_reduce_sum(xv * vW2[t], sbuf);
    const float d2 = block_reduce_sum(xv * xv, sbuf);
    const float d3 = block_reduce_sum(zsum, sbuf);
    if (t == 0) {
        const float icnn_x = d1 + vb2[0] + d3;
        const float diff = icnn_x - ic0[0];
        sS[b]  = fminf(fmaxf(diff / C_PSD_D, 0.0f), 1.0f);
        sVx[b] = rehu_f(diff, C_PSD_D) + C_EPS * d2;
    }
}

// in place: a2[b,j] -> s[b] * spU1[j] * drehu(a2[b,j], 0.01)   (no /H: vU1.shape[0]==1)
__global__ void ga2_kernel(float* __restrict__ a2, const float* __restrict__ sS,
                           const float* __restrict__ spU1, long n) {
    long i = (long)blockIdx.x * blockDim.x + threadIdx.x;
    const long stride = (long)gridDim.x * blockDim.x;
    for (; i < n; i += stride) {
        const int b = (int)(i >> 11);
        const int j = (int)(i & (NH - 1));
        a2[i] = sS[b] * spU1[j] * drehu_f(a2[i], C_REHU_D);
    }
}

// gV[b,c] = s[b]*vW2[c] + 2*eps*x[b,c]
__global__ void gvinit_kernel(float* __restrict__ gV, const float* __restrict__ sS,
                              const float* __restrict__ vW2, const float* __restrict__ x,
                              long n) {
    long i = (long)blockIdx.x * blockDim.x + threadIdx.x;
    const long stride = (long)gridDim.x * blockDim.x;
    for (; i < n; i += stride) {
        const int b = (int)(i >> 8);
        const int c = (int)(i & (ND - 1));
        gV[i] = sS[b] * vW2[c] + 2.0f * C_EPS * x[i];
    }
}

// per row: num = relu(gV.fx + alpha*Vx); den = gV.gV; out = fx - gV*num/den (first 255 cols)
__global__ __launch_bounds__(256) void final_kernel(
    float* __restrict__ out, const float* __restrict__ gV,
    const float* __restrict__ fx, const float* __restrict__ sVx)
{
    __shared__ float sbuf[4];
    __shared__ float scoef;
    const int b = blockIdx.x;
    const int t = threadIdx.x;
    const float g = gV[(size_t)b * ND + t];
    const float f = fx[(size_t)b * ND + t];
    const float gf = block_reduce_sum(g * f, sbuf);
    const float gg = block_reduce_sum(g * g, sbuf);
    if (t == 0) {
        const float num = fmaxf(gf + C_ALPHA * sVx[b], 0.0f);
        scoef = num / gg;
    }
    __syncthreads();
    const float coef = scoef;
    if (t < NOUT) out[(size_t)b * NOUT + t] = f - g * coef;
}

extern "C" void kernel_launch(void* const* d_in, const int* in_sizes, int n_in,
                              void* d_out, int out_size, void* d_ws, size_t ws_size,
                              hipStream_t stream)
{
    const float* x   = (const float*)d_in[0];
    const float* fW0 = (const float*)d_in[1];
    const float* fb0 = (const float*)d_in[2];
    const float* fW1 = (const float*)d_in[3];
    const float* fb1 = (const float*)d_in[4];
    const float* fW2 = (const float*)d_in[5];
    const float* fb2 = (const float*)d_in[6];
    const float* vW0 = (const float*)d_in[7];
    const float* vb0 = (const float*)d_in[8];
    const float* vW1 = (const float*)d_in[9];
    const float* vb1 = (const float*)d_in[10];
    const float* vW2 = (const float*)d_in[11];
    const float* vb2 = (const float*)d_in[12];
    const float* vU0 = (const float*)d_in[13];
    const float* vU1 = (const float*)d_in[14];
    float* out = (float*)d_out;
    (void)in_sizes; (void)n_in; (void)out_size; (void)d_ws; (void)ws_size;

    float *spU0, *spU1, *z10, *a20, *ic0, *bufA, *bufB, *fxb, *gVb, *sS, *sVx;
    hipGetSymbolAddress((void**)&spU0, HIP_SYMBOL(g_spU0));
    hipGetSymbolAddress((void**)&spU1, HIP_SYMBOL(g_spU1));
    hipGetSymbolAddress((void**)&z10,  HIP_SYMBOL(g_z10));
    hipGetSymbolAddress((void**)&a20,  HIP_SYMBOL(g_a20));
    hipGetSymbolAddress((void**)&ic0,  HIP_SYMBOL(g_ic0));
    hipGetSymbolAddress((void**)&bufA, HIP_SYMBOL(g_bufA));
    hipGetSymbolAddress((void**)&bufB, HIP_SYMBOL(g_bufB));
    hipGetSymbolAddress((void**)&fxb,  HIP_SYMBOL(g_fx));
    hipGetSymbolAddress((void**)&gVb,  HIP_SYMBOL(g_gV));
    hipGetSymbolAddress((void**)&sS,   HIP_SYMBOL(g_sS));
    hipGetSymbolAddress((void**)&sVx,  HIP_SYMBOL(g_sVx));

    const dim3 blk(256);
    auto g2 = [](int N, int M) { return dim3((unsigned)((N + 63) / 64), (unsigned)(M / 64)); };

    // constants / small precomputes (once)
    ew_softplus<<<2048, 256, 0, stream>>>(spU0, vU0, (long)NH * NH);
    ew_softplus<<<8, 256, 0, stream>>>(spU1, vU1, NH);
    ew_rehu<<<8, 256, 0, stream>>>(z10, vb0, NH);
    a20_kernel<<<NH, 256, 0, stream>>>(a20, z10, spU0, vb1);
    icnn0_kernel<<<1, 256, 0, stream>>>(ic0, a20, spU1, vb2);

    for (int c = 0; c < NCHUNK; ++c) {
        const float* xc = x + (size_t)c * CH * ND;
        float* outc = out + (size_t)c * CH * NOUT;

        // fhat MLP
        gemm_kernel<1,0,1,0,1><<<g2(NH, CH), blk, 0, stream>>>(bufA, xc, fW0, fb0, nullptr, CH, NH, ND, NH, 1.0f);
        gemm_kernel<1,0,1,0,1><<<g2(NH, CH), blk, 0, stream>>>(bufB, bufA, fW1, fb1, nullptr, CH, NH, NH, NH, 1.0f);
        gemm_kernel<1,0,0,0,1><<<g2(NOUT, CH), blk, 0, stream>>>(fxb, bufB, fW2, fb2, nullptr, CH, NOUT, NH, ND, 1.0f);
        set_ones_col<<<(CH + 255) / 256, 256, 0, stream>>>(fxb, CH);

        // ICNN forward: a1 (raw, bufA), a2 = x@vW1^T + vb1 + rehu(a1)@spU0^T / H  (bufB)
        gemm_kernel<1,0,0,0,1><<<g2(NH, CH), blk, 0, stream>>>(bufA, xc, vW0, vb0, nullptr, CH, NH, ND, NH, 1.0f);
        gemm_kernel<1,0,0,0,1><<<g2(NH, CH), blk, 0, stream>>>(bufB, xc, vW1, vb1, nullptr, CH, NH, ND, NH, 1.0f);
        gemm_kernel<1,1,0,1,0><<<g2(NH, CH), blk, 0, stream>>>(bufB, bufA, spU0, nullptr, nullptr, CH, NH, NH, NH, 1.0f / NH);
        rowstats_kernel<<<CH, 256, 0, stream>>>(sS, sVx, xc, bufB, spU1, vW2, vb2, ic0);

        // backward
        ga2_kernel<<<2048, 256, 0, stream>>>(bufB, sS, spU1, (long)CH * NH);          // bufB = g_a2
        gemm_kernel<0,0,3,0,0><<<g2(NH, CH), blk, 0, stream>>>(bufA, bufB, spU0, nullptr, bufA, CH, NH, NH, NH, 1.0f / NH); // bufA = g_a1
        gvinit_kernel<<<512, 256, 0, stream>>>(gVb, sS, vW2, xc, (long)CH * ND);
        gemm_kernel<0,0,0,1,0><<<g2(ND, CH), blk, 0, stream>>>(gVb, bufB, vW1, nullptr, nullptr, CH, ND, NH, ND, 1.0f);
        gemm_kernel<0,0,0,1,0><<<g2(ND, CH), blk, 0, stream>>>(gVb, bufA, vW0, nullptr, nullptr, CH, ND, NH, ND, 1.0f);

        final_kernel<<<CH, 256, 0, stream>>>(outc, gVb, fxb, sVx);
    }
}

// Round 4
// 1495.488 us; speedup vs baseline: 6.7476x; 6.7476x over previous
//
#include <hip/hip_runtime.h>
#include <hip/hip_bf16.h>
#include <math.h>

#define NB 16384
#define ND 256
#define NH 2048
#define NOUT 255

constexpr float C_ALPHA  = 0.01f;
constexpr float C_REHU_D = 0.01f;
constexpr float C_PSD_D  = 1.0f;
constexpr float C_EPS    = 1e-5f;

typedef unsigned short u16;
typedef short bf16x8 __attribute__((ext_vector_type(8)));
typedef float f32x4 __attribute__((ext_vector_type(4)));

// ---- scratch in device globals (independent of ws_size) ----
__device__ u16   g_xbf [(size_t)NB * ND];
__device__ u16   g_buf1[(size_t)NB * NH];   // h1, later g_a2
__device__ u16   g_buf2[(size_t)NB * NH];   // h2, later g_a1
__device__ u16   g_z1  [(size_t)NB * NH];
__device__ float g_a1f [(size_t)NB * NH];
__device__ float g_a2f [(size_t)NB * NH];
__device__ float g_fxb [(size_t)NB * ND];
__device__ float g_gVb [(size_t)NB * ND];
__device__ u16   g_fW0b[(size_t)NH * ND];
__device__ u16   g_fW1b[(size_t)NH * NH];
__device__ u16   g_fW2b[(size_t)ND * NH];   // padded: row 255 = 0
__device__ u16   g_vW0b[(size_t)NH * ND];
__device__ u16   g_vW1b[(size_t)NH * ND];
__device__ u16   g_spU0b [(size_t)NH * NH];
__device__ u16   g_spU0Tb[(size_t)NH * NH];
__device__ u16   g_vW0Tb[(size_t)ND * NH];
__device__ u16   g_vW1Tb[(size_t)ND * NH];
__device__ float g_fb2p[ND];
__device__ float g_spU1[NH];
__device__ float g_z10[NH];
__device__ float g_a20[NH];
__device__ float g_ic0[1];
__device__ float g_sS [NB];
__device__ float g_sVx[NB];

__device__ __forceinline__ float softplus_f(float x) {
    return fmaxf(x, 0.0f) + log1pf(expf(-fabsf(x)));
}
__device__ __forceinline__ float rehu_f(float x, float d) {
    float t = x * fabsf(x) / (2.0f * d);
    t = fminf(fmaxf(t, 0.0f), 0.5f * d);
    return fmaxf(t, x - 0.5f * d);
}
__device__ __forceinline__ float drehu_f(float x, float d) {
    return fminf(fmaxf(x / d, 0.0f), 1.0f);
}
__device__ __forceinline__ u16 f2b(float v) {
    __hip_bfloat16 b = __float2bfloat16(v);
    return *reinterpret_cast<u16*>(&b);
}

// valid result on thread 0 only
__device__ __forceinline__ float block_reduce_sum(float v, float* sbuf) {
    #pragma unroll
    for (int off = 32; off > 0; off >>= 1) v += __shfl_down(v, off, 64);
    const int lane = threadIdx.x & 63;
    const int wid  = threadIdx.x >> 6;
    if (lane == 0) sbuf[wid] = v;
    __syncthreads();
    float r = 0.0f;
    if (wid == 0) {
        r = (lane < 4) ? sbuf[lane] : 0.0f;
        r += __shfl_down(r, 2, 64);
        r += __shfl_down(r, 1, 64);
    }
    __syncthreads();
    return r;
}

// ======================= bf16 MFMA GEMM (m97 structure) =======================
// Y = alpha * (A @ Bm^T) [+ bias]; A [M,K] bf16, Bm [N,K] bf16, accum fp32.
// MODE 0: Ybf = bf16(relu(v + bias))
// MODE 1: Y32 = v + bias
// MODE 2: Y32 = v + bias; Ybf = bf16(rehu(v+bias, 0.01))
// MODE 3: Y32 += v            (bias unused)
// MODE 4: Ybf = bf16(v * drehu(aux, 0.01))
#define BM 128
#define BN 128
#define BK 32

template<int MODE>
__global__ __launch_bounds__(256) void mfma_gemm(
    float* __restrict__ Y32, u16* __restrict__ Ybf,
    const u16* __restrict__ A, const u16* __restrict__ Bm,
    const float* __restrict__ bias, const float* __restrict__ aux,
    int M, int N, int K, float alpha)
{
    __shared__ u16 As[BM * BK];
    __shared__ u16 Bs[BN * BK];

    const int ntn = N >> 7;
    const int nwg = gridDim.x;
    const int bid = blockIdx.x;
    const int swz = (bid & 7) * (nwg >> 3) + (bid >> 3);   // XCD swizzle (nwg % 8 == 0)
    const int tm = swz / ntn, tn = swz % ntn;
    const int row0 = tm * BM, col0 = tn * BN;

    const int tid  = threadIdx.x;
    const int lane = tid & 63;
    const int wave = tid >> 6;
    const int wr = wave >> 1, wc = wave & 1;

    f32x4 acc[4][4] = {};

    // staging addresses: thread t -> 16B at (row0 + t/4, (t%4)*8)
    const u16* Ag = A + (size_t)(row0 + (tid >> 2)) * K + ((tid & 3) << 3);
    const u16* Bg = Bm + (size_t)(col0 + (tid >> 2)) * K + ((tid & 3) << 3);
    char* AsB = (char*)As + wave * 1024;
    char* BsB = (char*)Bs + wave * 1024;

    const int lr = lane & 15;
    const int lk = (lane >> 4) << 3;

    for (int k0 = 0; k0 < K; k0 += BK) {
        __builtin_amdgcn_global_load_lds((const __attribute__((address_space(1))) void*)(Ag + k0),
                                         (__attribute__((address_space(3))) void*)(AsB), 16, 0, 0);
        __builtin_amdgcn_global_load_lds((const __attribute__((address_space(1))) void*)(Ag + (size_t)64 * K + k0),
                                         (__attribute__((address_space(3))) void*)(AsB + 4096), 16, 0, 0);
        __builtin_amdgcn_global_load_lds((const __attribute__((address_space(1))) void*)(Bg + k0),
                                         (__attribute__((address_space(3))) void*)(BsB), 16, 0, 0);
        __builtin_amdgcn_global_load_lds((const __attribute__((address_space(1))) void*)(Bg + (size_t)64 * K + k0),
                                         (__attribute__((address_space(3))) void*)(BsB + 4096), 16, 0, 0);
        __syncthreads();

        bf16x8 af[4], bfr[4];
        #pragma unroll
        for (int m = 0; m < 4; ++m)
            af[m] = *reinterpret_cast<const bf16x8*>(&As[(wr * 64 + m * 16 + lr) * BK + lk]);
        #pragma unroll
        for (int n = 0; n < 4; ++n)
            bfr[n] = *reinterpret_cast<const bf16x8*>(&Bs[(wc * 64 + n * 16 + lr) * BK + lk]);
        #pragma unroll
        for (int m = 0; m < 4; ++m)
            #pragma unroll
            for (int n = 0; n < 4; ++n)
                acc[m][n] = __builtin_amdgcn_mfma_f32_16x16x32_bf16(af[m], bfr[n], acc[m][n], 0, 0, 0);
        __syncthreads();
    }

    const int rr = (lane >> 4) << 2;
    #pragma unroll
    for (int m = 0; m < 4; ++m) {
        #pragma unroll
        for (int n = 0; n < 4; ++n) {
            const int col = col0 + wc * 64 + n * 16 + lr;
            float bv = 0.0f;
            if (MODE <= 2) bv = bias[col];
            #pragma unroll
            for (int i = 0; i < 4; ++i) {
                const int row = row0 + wr * 64 + m * 16 + rr + i;
                const size_t idx = (size_t)row * N + col;
                float v = alpha * acc[m][n][i] + bv;
                if (MODE == 0) {
                    Ybf[idx] = f2b(fmaxf(v, 0.0f));
                } else if (MODE == 1) {
                    Y32[idx] = v;
                } else if (MODE == 2) {
                    Y32[idx] = v;
                    Ybf[idx] = f2b(rehu_f(v, C_REHU_D));
                } else if (MODE == 3) {
                    Y32[idx] += v;
                } else { // MODE == 4
                    Ybf[idx] = f2b(v * drehu_f(aux[idx], C_REHU_D));
                }
            }
        }
    }
}

// ======================= small helper kernels =======================
template<int OP>  // 0 identity, 1 softplus
__global__ void cast_kernel(u16* __restrict__ dst, const float* __restrict__ src, long n) {
    long i = (long)blockIdx.x * blockDim.x + threadIdx.x;
    const long stride = (long)gridDim.x * blockDim.x;
    for (; i < n; i += stride) {
        float v = src[i];
        if (OP) v = softplus_f(v);
        dst[i] = f2b(v);
    }
}

__global__ void castpad_kernel(u16* __restrict__ dst, const float* __restrict__ src,
                               long nsrc, long ntot) {
    long i = (long)blockIdx.x * blockDim.x + threadIdx.x;
    const long stride = (long)gridDim.x * blockDim.x;
    for (; i < ntot; i += stride) dst[i] = (i < nsrc) ? f2b(src[i]) : (u16)0;
}

template<int OP>  // dst[c*R + r] = op(src[r*C + c]); grid (C/32, R/32), block (32,8)
__global__ __launch_bounds__(256) void transpose_cast_kernel(
    u16* __restrict__ dst, const float* __restrict__ src, int R, int C)
{
    __shared__ float t[32][33];
    const int c0 = blockIdx.x * 32, r0 = blockIdx.y * 32;
    for (int i = threadIdx.y; i < 32; i += 8)
        t[i][threadIdx.x] = src[(size_t)(r0 + i) * C + c0 + threadIdx.x];
    __syncthreads();
    for (int i = threadIdx.y; i < 32; i += 8) {
        float v = t[threadIdx.x][i];
        if (OP) v = softplus_f(v);
        dst[(size_t)(c0 + i) * R + r0 + threadIdx.x] = f2b(v);
    }
}

__global__ void ew_softplus_f32(float* __restrict__ dst, const float* __restrict__ src, long n) {
    long i = (long)blockIdx.x * blockDim.x + threadIdx.x;
    const long stride = (long)gridDim.x * blockDim.x;
    for (; i < n; i += stride) dst[i] = softplus_f(src[i]);
}

__global__ void ew_rehu_f32(float* __restrict__ dst, const float* __restrict__ src, long n) {
    long i = (long)blockIdx.x * blockDim.x + threadIdx.x;
    const long stride = (long)gridDim.x * blockDim.x;
    for (; i < n; i += stride) dst[i] = rehu_f(src[i], C_REHU_D);
}

__global__ void fb2p_kernel(float* __restrict__ dst, const float* __restrict__ fb2) {
    const int c = threadIdx.x;
    dst[c] = (c < NOUT) ? fb2[c] : 1.0f;
}

// a2_0[j] = vb1[j] + (1/H) * sum_k z1_0[k] * softplus(vU0[j,k])
__global__ __launch_bounds__(256) void a20_kernel(
    float* __restrict__ a20, const float* __restrict__ z10,
    const float* __restrict__ vU0, const float* __restrict__ vb1)
{
    __shared__ float sbuf[4];
    const int j = blockIdx.x;
    float sum = 0.0f;
    const float* row = vU0 + (size_t)j * NH;
    for (int k = threadIdx.x; k < NH; k += 256) sum += z10[k] * softplus_f(row[k]);
    sum = block_reduce_sum(sum, sbuf);
    if (threadIdx.x == 0) a20[j] = vb1[j] + sum * (1.0f / NH);
}

// icnn0 = vb2 + sum_j rehu(a2_0[j]) * spU1[j]   (vU1.shape[0] == 1 -> no /H)
__global__ __launch_bounds__(256) void icnn0_kernel(
    float* __restrict__ ic0, const float* __restrict__ a20,
    const float* __restrict__ spU1, const float* __restrict__ vb2)
{
    __shared__ float sbuf[4];
    float sum = 0.0f;
    for (int j = threadIdx.x; j < NH; j += 256) sum += rehu_f(a20[j], C_REHU_D) * spU1[j];
    sum = block_reduce_sum(sum, sbuf);
    if (threadIdx.x == 0) ic0[0] = vb2[0] + sum;
}

__global__ __launch_bounds__(256) void rowstats_kernel(
    float* __restrict__ sS, float* __restrict__ sVx,
    const float* __restrict__ x, const float* __restrict__ a2,
    const float* __restrict__ spU1, const float* __restrict__ vW2,
    const float* __restrict__ vb2, const float* __restrict__ ic0)
{
    __shared__ float sbuf[4];
    const int b = blockIdx.x;
    const int t = threadIdx.x;
    const float xv = x[(size_t)b * ND + t];
    float zsum = 0.0f;
    const float* a2r = a2 + (size_t)b * NH;
    for (int j = t; j < NH; j += 256) zsum += rehu_f(a2r[j], C_REHU_D) * spU1[j];
    const float d1 = block_reduce_sum(xv * vW2[t], sbuf);
    const float d2 = block_reduce_sum(xv * xv, sbuf);
    const float d3 = block_reduce_sum(zsum, sbuf);
    if (t == 0) {
        const float icnn_x = d1 + vb2[0] + d3;
        const float diff = icnn_x - ic0[0];
        sS[b]  = fminf(fmaxf(diff / C_PSD_D, 0.0f), 1.0f);
        sVx[b] = rehu_f(diff, C_PSD_D) + C_EPS * d2;
    }
}

// g_a2[b,j] = bf16( s[b] * spU1[j] * drehu(a2[b,j], 0.01) )
__global__ void ga2_kernel(u16* __restrict__ ga2, const float* __restrict__ a2,
                           const float* __restrict__ sS, const float* __restrict__ spU1, long n) {
    long i = (long)blockIdx.x * blockDim.x + threadIdx.x;
    const long stride = (long)gridDim.x * blockDim.x;
    for (; i < n; i += stride) {
        const int b = (int)(i >> 11);
        const int j = (int)(i & (NH - 1));
        ga2[i] = f2b(sS[b] * spU1[j] * drehu_f(a2[i], C_REHU_D));
    }
}

// gV[b,c] = s[b]*vW2[c] + 2*eps*x[b,c]
__global__ void gvinit_kernel(float* __restrict__ gV, const float* __restrict__ sS,
                              const float* __restrict__ vW2, const float* __restrict__ x,
                              long n) {
    long i = (long)blockIdx.x * blockDim.x + threadIdx.x;
    const long stride = (long)gridDim.x * blockDim.x;
    for (; i < n; i += stride) {
        const int b = (int)(i >> 8);
        const int c = (int)(i & (ND - 1));
        gV[i] = sS[b] * vW2[c] + 2.0f * C_EPS * x[i];
    }
}

__global__ __launch_bounds__(256) void final_kernel(
    float* __restrict__ out, const float* __restrict__ gV,
    const float* __restrict__ fx, const float* __restrict__ sVx)
{
    __shared__ float sbuf[4];
    __shared__ float scoef;
    const int b = blockIdx.x;
    const int t = threadIdx.x;
    const float g = gV[(size_t)b * ND + t];
    const float f = fx[(size_t)b * ND + t];
    const float gf = block_reduce_sum(g * f, sbuf);
    const float gg = block_reduce_sum(g * g, sbuf);
    if (t == 0) {
        const float num = fmaxf(gf + C_ALPHA * sVx[b], 0.0f);
        scoef = num / gg;
    }
    __syncthreads();
    const float coef = scoef;
    if (t < NOUT) out[(size_t)b * NOUT + t] = f - g * coef;
}

extern "C" void kernel_launch(void* const* d_in, const int* in_sizes, int n_in,
                              void* d_out, int out_size, void* d_ws, size_t ws_size,
                              hipStream_t stream)
{
    const float* x   = (const float*)d_in[0];
    const float* fW0 = (const float*)d_in[1];
    const float* fb0 = (const float*)d_in[2];
    const float* fW1 = (const float*)d_in[3];
    const float* fb1 = (const float*)d_in[4];
    const float* fW2 = (const float*)d_in[5];
    const float* fb2 = (const float*)d_in[6];
    const float* vW0 = (const float*)d_in[7];
    const float* vb0 = (const float*)d_in[8];
    const float* vW1 = (const float*)d_in[9];
    const float* vb1 = (const float*)d_in[10];
    const float* vW2 = (const float*)d_in[11];
    const float* vb2 = (const float*)d_in[12];
    const float* vU0 = (const float*)d_in[13];
    const float* vU1 = (const float*)d_in[14];
    float* out = (float*)d_out;
    (void)in_sizes; (void)n_in; (void)out_size; (void)d_ws; (void)ws_size;

    u16 *xbf, *buf1, *buf2, *z1b, *fW0b, *fW1b, *fW2b, *vW0b, *vW1b, *spU0b, *spU0Tb, *vW0Tb, *vW1Tb;
    float *a1f, *a2f, *fxb, *gVb, *fb2p, *spU1, *z10, *a20, *ic0, *sS, *sVx;
    hipGetSymbolAddress((void**)&xbf,   HIP_SYMBOL(g_xbf));
    hipGetSymbolAddress((void**)&buf1,  HIP_SYMBOL(g_buf1));
    hipGetSymbolAddress((void**)&buf2,  HIP_SYMBOL(g_buf2));
    hipGetSymbolAddress((void**)&z1b,   HIP_SYMBOL(g_z1));
    hipGetSymbolAddress((void**)&a1f,   HIP_SYMBOL(g_a1f));
    hipGetSymbolAddress((void**)&a2f,   HIP_SYMBOL(g_a2f));
    hipGetSymbolAddress((void**)&fxb,   HIP_SYMBOL(g_fxb));
    hipGetSymbolAddress((void**)&gVb,   HIP_SYMBOL(g_gVb));
    hipGetSymbolAddress((void**)&fW0b,  HIP_SYMBOL(g_fW0b));
    hipGetSymbolAddress((void**)&fW1b,  HIP_SYMBOL(g_fW1b));
    hipGetSymbolAddress((void**)&fW2b,  HIP_SYMBOL(g_fW2b));
    hipGetSymbolAddress((void**)&vW0b,  HIP_SYMBOL(g_vW0b));
    hipGetSymbolAddress((void**)&vW1b,  HIP_SYMBOL(g_vW1b));
    hipGetSymbolAddress((void**)&spU0b, HIP_SYMBOL(g_spU0b));
    hipGetSymbolAddress((void**)&spU0Tb,HIP_SYMBOL(g_spU0Tb));
    hipGetSymbolAddress((void**)&vW0Tb, HIP_SYMBOL(g_vW0Tb));
    hipGetSymbolAddress((void**)&vW1Tb, HIP_SYMBOL(g_vW1Tb));
    hipGetSymbolAddress((void**)&fb2p,  HIP_SYMBOL(g_fb2p));
    hipGetSymbolAddress((void**)&spU1,  HIP_SYMBOL(g_spU1));
    hipGetSymbolAddress((void**)&z10,   HIP_SYMBOL(g_z10));
    hipGetSymbolAddress((void**)&a20,   HIP_SYMBOL(g_a20));
    hipGetSymbolAddress((void**)&ic0,   HIP_SYMBOL(g_ic0));
    hipGetSymbolAddress((void**)&sS,    HIP_SYMBOL(g_sS));
    hipGetSymbolAddress((void**)&sVx,   HIP_SYMBOL(g_sVx));

    auto gg = [](int M, int N) { return dim3((unsigned)((M / 128) * (N / 128))); };
    const dim3 blk(256);

    // ---- one-time precomputes (weights -> bf16, scalars) ----
    cast_kernel<0><<<1024, 256, 0, stream>>>(xbf, x, (long)NB * ND);
    cast_kernel<0><<<512, 256, 0, stream>>>(fW0b, fW0, (long)NH * ND);
    cast_kernel<0><<<2048, 256, 0, stream>>>(fW1b, fW1, (long)NH * NH);
    castpad_kernel<<<512, 256, 0, stream>>>(fW2b, fW2, (long)NOUT * NH, (long)ND * NH);
    cast_kernel<0><<<512, 256, 0, stream>>>(vW0b, vW0, (long)NH * ND);
    cast_kernel<0><<<512, 256, 0, stream>>>(vW1b, vW1, (long)NH * ND);
    cast_kernel<1><<<2048, 256, 0, stream>>>(spU0b, vU0, (long)NH * NH);
    transpose_cast_kernel<1><<<dim3(64, 64), dim3(32, 8), 0, stream>>>(spU0Tb, vU0, NH, NH);
    transpose_cast_kernel<0><<<dim3(8, 64), dim3(32, 8), 0, stream>>>(vW0Tb, vW0, NH, ND);
    transpose_cast_kernel<0><<<dim3(8, 64), dim3(32, 8), 0, stream>>>(vW1Tb, vW1, NH, ND);
    ew_softplus_f32<<<8, 256, 0, stream>>>(spU1, vU1, NH);
    ew_rehu_f32<<<8, 256, 0, stream>>>(z10, vb0, NH);
    fb2p_kernel<<<1, 256, 0, stream>>>(fb2p, fb2);
    a20_kernel<<<NH, 256, 0, stream>>>(a20, z10, vU0, vb1);
    icnn0_kernel<<<1, 256, 0, stream>>>(ic0, a20, spU1, vb2);

    // ---- fhat MLP ----
    mfma_gemm<0><<<gg(NB, NH), blk, 0, stream>>>(nullptr, buf1, xbf, fW0b, fb0, nullptr, NB, NH, ND, 1.0f);
    mfma_gemm<0><<<gg(NB, NH), blk, 0, stream>>>(nullptr, buf2, buf1, fW1b, fb1, nullptr, NB, NH, NH, 1.0f);
    mfma_gemm<1><<<gg(NB, ND), blk, 0, stream>>>(fxb, nullptr, buf2, fW2b, fb2p, nullptr, NB, ND, NH, 1.0f);

    // ---- ICNN forward ----
    mfma_gemm<2><<<gg(NB, NH), blk, 0, stream>>>(a1f, z1b, xbf, vW0b, vb0, nullptr, NB, NH, ND, 1.0f);
    mfma_gemm<1><<<gg(NB, NH), blk, 0, stream>>>(a2f, nullptr, xbf, vW1b, vb1, nullptr, NB, NH, ND, 1.0f);
    mfma_gemm<3><<<gg(NB, NH), blk, 0, stream>>>(a2f, nullptr, z1b, spU0b, nullptr, nullptr, NB, NH, NH, 1.0f / NH);
    rowstats_kernel<<<NB, 256, 0, stream>>>(sS, sVx, x, a2f, spU1, vW2, vb2, ic0);

    // ---- backward ----
    ga2_kernel<<<4096, 256, 0, stream>>>(buf1, a2f, sS, spU1, (long)NB * NH);        // buf1 = g_a2 (bf16)
    mfma_gemm<4><<<gg(NB, NH), blk, 0, stream>>>(nullptr, buf2, buf1, spU0Tb, nullptr, a1f, NB, NH, NH, 1.0f / NH); // buf2 = g_a1
    gvinit_kernel<<<2048, 256, 0, stream>>>(gVb, sS, vW2, x, (long)NB * ND);
    mfma_gemm<3><<<gg(NB, ND), blk, 0, stream>>>(gVb, nullptr, buf1, vW1Tb, nullptr, nullptr, NB, ND, NH, 1.0f);
    mfma_gemm<3><<<gg(NB, ND), blk, 0, stream>>>(gVb, nullptr, buf2, vW0Tb, nullptr, nullptr, NB, ND, NH, 1.0f);

    final_kernel<<<NB, 256, 0, stream>>>(out, gVb, fxb, sVx);
}

// Round 5
// 1381.426 us; speedup vs baseline: 7.3048x; 1.0826x over previous
//
#include <hip/hip_runtime.h>
#include <hip/hip_bf16.h>
#include <math.h>

#define NB 16384
#define ND 256
#define NH 2048
#define NOUT 255

constexpr float C_ALPHA  = 0.01f;
constexpr float C_REHU_D = 0.01f;
constexpr float C_PSD_D  = 1.0f;
constexpr float C_EPS    = 1e-5f;

typedef unsigned short u16;
typedef short bf16x8 __attribute__((ext_vector_type(8)));
typedef float f32x4 __attribute__((ext_vector_type(4)));

// ---- scratch in device globals ----
__device__ u16   g_xbf [(size_t)NB * ND];
__device__ u16   g_buf1[(size_t)NB * NH];   // h1 -> g_a2
__device__ u16   g_buf2[(size_t)NB * NH];   // h2 -> g_a1
__device__ u16   g_z1  [(size_t)NB * NH];   // rehu(a1) bf16
__device__ u16   g_a2b [(size_t)NB * NH];   // a2 bf16
__device__ float g_fxb [(size_t)NB * ND];
__device__ float g_gVb [(size_t)NB * ND];
__device__ u16   g_fW0b[(size_t)NH * ND];
__device__ u16   g_fW1b[(size_t)NH * NH];
__device__ u16   g_fW2b[(size_t)ND * NH];   // padded: row 255 = 0
__device__ u16   g_vW0b[(size_t)NH * ND];
__device__ u16   g_vW1b[(size_t)NH * ND];
__device__ u16   g_spU0b [(size_t)NH * NH];  // softplus(vU0)/NH
__device__ u16   g_spU0Tb[(size_t)NH * NH];  // transpose of above
__device__ u16   g_vW0Tb[(size_t)ND * NH];
__device__ u16   g_vW1Tb[(size_t)ND * NH];
__device__ float g_fb2p[ND];
__device__ float g_spU1[NH];
__device__ float g_z10[NH];
__device__ float g_a20[NH];
__device__ float g_ic0[1];
__device__ float g_zacc[NB];
__device__ float g_sS [NB];
__device__ float g_sVx[NB];

__device__ __forceinline__ float softplus_f(float x) {
    return fmaxf(x, 0.0f) + log1pf(expf(-fabsf(x)));
}
__device__ __forceinline__ float rehu_f(float x, float d) {
    float t = x * fabsf(x) / (2.0f * d);
    t = fminf(fmaxf(t, 0.0f), 0.5f * d);
    return fmaxf(t, x - 0.5f * d);
}
__device__ __forceinline__ float drehu_f(float x, float d) {
    return fminf(fmaxf(x / d, 0.0f), 1.0f);
}
__device__ __forceinline__ u16 f2b(float v) {
    __hip_bfloat16 b = __float2bfloat16(v);
    return *reinterpret_cast<u16*>(&b);
}
__device__ __forceinline__ float b2f(u16 v) {
    unsigned u = ((unsigned)v) << 16;
    return __uint_as_float(u);
}

// valid result on thread 0 only
__device__ __forceinline__ float block_reduce_sum(float v, float* sbuf) {
    #pragma unroll
    for (int off = 32; off > 0; off >>= 1) v += __shfl_down(v, off, 64);
    const int lane = threadIdx.x & 63;
    const int wid  = threadIdx.x >> 6;
    if (lane == 0) sbuf[wid] = v;
    __syncthreads();
    float r = 0.0f;
    if (wid == 0) {
        r = (lane < 4) ? sbuf[lane] : 0.0f;
        r += __shfl_down(r, 2, 64);
        r += __shfl_down(r, 1, 64);
    }
    __syncthreads();
    return r;
}

// ======================= bf16 MFMA GEMM (m97 structure) =======================
// Y = (A @ Bm^T) [+ bias] with optional second K-segment (A2 @ B2^T, stride K2).
// MODE 0: Ybf = bf16(relu(v+bias))
// MODE 1: Y32 = v + bias
// MODE 2: Ybf = bf16(rehu(v+bias, 0.01))
// MODE 3: Ybf = bf16(v+bias); zacc[row] += sum_cols rehu(v+bias)*spU1[col]  (atomic)
// MODE 4: Ybf = bf16(v * min(1, sqrt(200*z1b[idx])))   (drehu from z1)
// MODE 5: atomicAdd(Y32+idx, v)  (split-K via blockIdx.y: koff = blockIdx.y*K)
#define BM 128
#define BN 128
#define BK 32

template<int MODE, int SEG2>
__global__ __launch_bounds__(256) void mfma_gemm(
    float* __restrict__ Y32, u16* __restrict__ Ybf,
    const u16* __restrict__ A, const u16* __restrict__ Bm, int lda, int ldb,
    const u16* __restrict__ A2, const u16* __restrict__ B2,
    const float* __restrict__ bias, const u16* __restrict__ auxb,
    float* __restrict__ zacc, const float* __restrict__ spU1,
    int M, int N, int K, int K2)
{
    __shared__ u16 As[BM * BK];
    __shared__ u16 Bs[BN * BK];

    const int ntn = N >> 7;
    const int nwg = gridDim.x;
    const int bid = blockIdx.x;
    const int swz = (bid & 7) * (nwg >> 3) + (bid >> 3);   // XCD swizzle (nwg % 8 == 0)
    const int tm = swz / ntn, tn = swz % ntn;
    const int row0 = tm * BM, col0 = tn * BN;
    const int koff = blockIdx.y * K;

    const int tid  = threadIdx.x;
    const int lane = tid & 63;
    const int wave = tid >> 6;
    const int wr = wave >> 1, wc = wave & 1;

    f32x4 acc[4][4] = {};

    char* AsB = (char*)As + wave * 1024;
    char* BsB = (char*)Bs + wave * 1024;
    const int lr = lane & 15;
    const int lk = (lane >> 4) << 3;

    #pragma unroll
    for (int seg = 0; seg < 1 + SEG2; ++seg) {
        const u16* Asrc = seg ? A2 : A;
        const u16* Bsrc = seg ? B2 : Bm;
        const int  kl = seg ? K2 : K;
        const long la = seg ? (long)K2 : (long)lda;
        const long lb = seg ? (long)K2 : (long)ldb;
        const u16* Ag = Asrc + (size_t)(row0 + (tid >> 2)) * la + ((tid & 3) << 3) + koff;
        const u16* Bg = Bsrc + (size_t)(col0 + (tid >> 2)) * lb + ((tid & 3) << 3) + koff;

        for (int k0 = 0; k0 < kl; k0 += BK) {
            __builtin_amdgcn_global_load_lds((const __attribute__((address_space(1))) void*)(Ag + k0),
                                             (__attribute__((address_space(3))) void*)(AsB), 16, 0, 0);
            __builtin_amdgcn_global_load_lds((const __attribute__((address_space(1))) void*)(Ag + (size_t)64 * la + k0),
                                             (__attribute__((address_space(3))) void*)(AsB + 4096), 16, 0, 0);
            __builtin_amdgcn_global_load_lds((const __attribute__((address_space(1))) void*)(Bg + k0),
                                             (__attribute__((address_space(3))) void*)(BsB), 16, 0, 0);
            __builtin_amdgcn_global_load_lds((const __attribute__((address_space(1))) void*)(Bg + (size_t)64 * lb + k0),
                                             (__attribute__((address_space(3))) void*)(BsB + 4096), 16, 0, 0);
            __syncthreads();

            bf16x8 af[4], bfr[4];
            #pragma unroll
            for (int m = 0; m < 4; ++m)
                af[m] = *reinterpret_cast<const bf16x8*>(&As[(wr * 64 + m * 16 + lr) * BK + lk]);
            #pragma unroll
            for (int n = 0; n < 4; ++n)
                bfr[n] = *reinterpret_cast<const bf16x8*>(&Bs[(wc * 64 + n * 16 + lr) * BK + lk]);
            #pragma unroll
            for (int m = 0; m < 4; ++m)
                #pragma unroll
                for (int n = 0; n < 4; ++n)
                    acc[m][n] = __builtin_amdgcn_mfma_f32_16x16x32_bf16(af[m], bfr[n], acc[m][n], 0, 0, 0);
            __syncthreads();
        }
    }

    const int rr = (lane >> 4) << 2;
    float rowpart[4][4];
    float sp[4];
    if (MODE == 3) {
        #pragma unroll
        for (int m = 0; m < 4; ++m)
            #pragma unroll
            for (int i = 0; i < 4; ++i) rowpart[m][i] = 0.0f;
        #pragma unroll
        for (int n = 0; n < 4; ++n) sp[n] = spU1[col0 + wc * 64 + n * 16 + lr];
    }

    #pragma unroll
    for (int m = 0; m < 4; ++m) {
        #pragma unroll
        for (int n = 0; n < 4; ++n) {
            const int col = col0 + wc * 64 + n * 16 + lr;
            float bv = 0.0f;
            if (MODE <= 3) bv = bias[col];
            #pragma unroll
            for (int i = 0; i < 4; ++i) {
                const int row = row0 + wr * 64 + m * 16 + rr + i;
                const size_t idx = (size_t)row * N + col;
                float v = acc[m][n][i] + bv;
                if (MODE == 0) {
                    Ybf[idx] = f2b(fmaxf(v, 0.0f));
                } else if (MODE == 1) {
                    Y32[idx] = v;
                } else if (MODE == 2) {
                    Ybf[idx] = f2b(rehu_f(v, C_REHU_D));
                } else if (MODE == 3) {
                    Ybf[idx] = f2b(v);
                    rowpart[m][i] += rehu_f(v, C_REHU_D) * sp[n];
                } else if (MODE == 4) {
                    const float z = b2f(auxb[idx]);
                    const float mask = fminf(sqrtf(200.0f * z), 1.0f);
                    Ybf[idx] = f2b(v * mask);
                } else { // MODE 5
                    atomicAdd(&Y32[idx], v);
                }
            }
        }
    }

    if (MODE == 3) {
        #pragma unroll
        for (int m = 0; m < 4; ++m) {
            #pragma unroll
            for (int i = 0; i < 4; ++i) {
                float s = rowpart[m][i];
                s += __shfl_xor(s, 1, 64);
                s += __shfl_xor(s, 2, 64);
                s += __shfl_xor(s, 4, 64);
                s += __shfl_xor(s, 8, 64);
                if (lr == 0) atomicAdd(&zacc[row0 + wr * 64 + m * 16 + rr + i], s);
            }
        }
    }
}

// ======================= small helper kernels =======================
template<int OP>  // 0 identity, 2 softplus/NH
__global__ void cast_kernel(u16* __restrict__ dst, const float* __restrict__ src, long n) {
    long i = (long)blockIdx.x * blockDim.x + threadIdx.x;
    const long stride = (long)gridDim.x * blockDim.x;
    for (; i < n; i += stride) {
        float v = src[i];
        if (OP == 2) v = softplus_f(v) * (1.0f / NH);
        dst[i] = f2b(v);
    }
}

__global__ void castpad_kernel(u16* __restrict__ dst, const float* __restrict__ src,
                               long nsrc, long ntot) {
    long i = (long)blockIdx.x * blockDim.x + threadIdx.x;
    const long stride = (long)gridDim.x * blockDim.x;
    for (; i < ntot; i += stride) dst[i] = (i < nsrc) ? f2b(src[i]) : (u16)0;
}

template<int OP>  // dst[c*R + r] = op(src[r*C + c]); grid (C/32, R/32), block (32,8)
__global__ __launch_bounds__(256) void transpose_cast_kernel(
    u16* __restrict__ dst, const float* __restrict__ src, int R, int C)
{
    __shared__ float t[32][33];
    const int c0 = blockIdx.x * 32, r0 = blockIdx.y * 32;
    for (int i = threadIdx.y; i < 32; i += 8)
        t[i][threadIdx.x] = src[(size_t)(r0 + i) * C + c0 + threadIdx.x];
    __syncthreads();
    for (int i = threadIdx.y; i < 32; i += 8) {
        float v = t[threadIdx.x][i];
        if (OP == 2) v = softplus_f(v) * (1.0f / NH);
        dst[(size_t)(c0 + i) * R + r0 + threadIdx.x] = f2b(v);
    }
}

__global__ void ew_softplus_f32(float* __restrict__ dst, const float* __restrict__ src, long n) {
    long i = (long)blockIdx.x * blockDim.x + threadIdx.x;
    const long stride = (long)gridDim.x * blockDim.x;
    for (; i < n; i += stride) dst[i] = softplus_f(src[i]);
}

__global__ void ew_rehu_f32(float* __restrict__ dst, const float* __restrict__ src, long n) {
    long i = (long)blockIdx.x * blockDim.x + threadIdx.x;
    const long stride = (long)gridDim.x * blockDim.x;
    for (; i < n; i += stride) dst[i] = rehu_f(src[i], C_REHU_D);
}

__global__ void clear_kernel(float* __restrict__ dst, long n) {
    long i = (long)blockIdx.x * blockDim.x + threadIdx.x;
    const long stride = (long)gridDim.x * blockDim.x;
    for (; i < n; i += stride) dst[i] = 0.0f;
}

__global__ void fb2p_kernel(float* __restrict__ dst, const float* __restrict__ fb2) {
    const int c = threadIdx.x;
    dst[c] = (c < NOUT) ? fb2[c] : 1.0f;
}

// a2_0[j] = vb1[j] + (1/H) * sum_k z1_0[k] * softplus(vU0[j,k])
__global__ __launch_bounds__(256) void a20_kernel(
    float* __restrict__ a20, const float* __restrict__ z10,
    const float* __restrict__ vU0, const float* __restrict__ vb1)
{
    __shared__ float sbuf[4];
    const int j = blockIdx.x;
    float sum = 0.0f;
    const float* row = vU0 + (size_t)j * NH;
    for (int k = threadIdx.x; k < NH; k += 256) sum += z10[k] * softplus_f(row[k]);
    sum = block_reduce_sum(sum, sbuf);
    if (threadIdx.x == 0) a20[j] = vb1[j] + sum * (1.0f / NH);
}

// icnn0 = vb2 + sum_j rehu(a2_0[j]) * spU1[j]   (vU1.shape[0] == 1 -> no /H)
__global__ __launch_bounds__(256) void icnn0_kernel(
    float* __restrict__ ic0, const float* __restrict__ a20,
    const float* __restrict__ spU1, const float* __restrict__ vb2)
{
    __shared__ float sbuf[4];
    float sum = 0.0f;
    for (int j = threadIdx.x; j < NH; j += 256) sum += rehu_f(a20[j], C_REHU_D) * spU1[j];
    sum = block_reduce_sum(sum, sbuf);
    if (threadIdx.x == 0) ic0[0] = vb2[0] + sum;
}

// per row b: d1 = x.vW2, d2 = ||x||^2; diff = d1 + vb2 + zacc[b] - ic0
// sS = clamp(diff,0,1); sVx = rehu(diff,1) + eps*d2; ga2[b,:] = sS*spU1*drehu(a2)
__global__ __launch_bounds__(256) void rowfin_ga2_kernel(
    float* __restrict__ sS, float* __restrict__ sVx, u16* __restrict__ ga2,
    const float* __restrict__ x, const u16* __restrict__ a2b,
    const float* __restrict__ zacc, const float* __restrict__ spU1,
    const float* __restrict__ vW2, const float* __restrict__ vb2,
    const float* __restrict__ ic0)
{
    __shared__ float sbuf[4];
    __shared__ float ssh;
    const int b = blockIdx.x;
    const int t = threadIdx.x;
    const float xv = x[(size_t)b * ND + t];
    const float d1 = block_reduce_sum(xv * vW2[t], sbuf);
    const float d2 = block_reduce_sum(xv * xv, sbuf);
    if (t == 0) {
        const float diff = d1 + vb2[0] + zacc[b] - ic0[0];
        const float s = fminf(fmaxf(diff / C_PSD_D, 0.0f), 1.0f);
        sS[b]  = s;
        sVx[b] = rehu_f(diff, C_PSD_D) + C_EPS * d2;
        ssh = s;
    }
    __syncthreads();
    const float s = ssh;
    const bf16x8 av = *reinterpret_cast<const bf16x8*>(a2b + (size_t)b * NH + t * 8);
    bf16x8 ov;
    #pragma unroll
    for (int j = 0; j < 8; ++j) {
        const float a2v = b2f((u16)av[j]);
        const float g = s * spU1[t * 8 + j] * drehu_f(a2v, C_REHU_D);
        ov[j] = (short)f2b(g);
    }
    *reinterpret_cast<bf16x8*>(ga2 + (size_t)b * NH + t * 8) = ov;
}

// gV[b,c] = s[b]*vW2[c] + 2*eps*x[b,c]
__global__ void gvinit_kernel(float* __restrict__ gV, const float* __restrict__ sS,
                              const float* __restrict__ vW2, const float* __restrict__ x,
                              long n) {
    long i = (long)blockIdx.x * blockDim.x + threadIdx.x;
    const long stride = (long)gridDim.x * blockDim.x;
    for (; i < n; i += stride) {
        const int b = (int)(i >> 8);
        const int c = (int)(i & (ND - 1));
        gV[i] = sS[b] * vW2[c] + 2.0f * C_EPS * x[i];
    }
}

__global__ __launch_bounds__(256) void final_kernel(
    float* __restrict__ out, const float* __restrict__ gV,
    const float* __restrict__ fx, const float* __restrict__ sVx)
{
    __shared__ float sbuf[4];
    __shared__ float scoef;
    const int b = blockIdx.x;
    const int t = threadIdx.x;
    const float g = gV[(size_t)b * ND + t];
    const float f = fx[(size_t)b * ND + t];
    const float gf = block_reduce_sum(g * f, sbuf);
    const float gg = block_reduce_sum(g * g, sbuf);
    if (t == 0) {
        const float num = fmaxf(gf + C_ALPHA * sVx[b], 0.0f);
        scoef = num / gg;
    }
    __syncthreads();
    const float coef = scoef;
    if (t < NOUT) out[(size_t)b * NOUT + t] = f - g * coef;
}

extern "C" void kernel_launch(void* const* d_in, const int* in_sizes, int n_in,
                              void* d_out, int out_size, void* d_ws, size_t ws_size,
                              hipStream_t stream)
{
    const float* x   = (const float*)d_in[0];
    const float* fW0 = (const float*)d_in[1];
    const float* fb0 = (const float*)d_in[2];
    const float* fW1 = (const float*)d_in[3];
    const float* fb1 = (const float*)d_in[4];
    const float* fW2 = (const float*)d_in[5];
    const float* fb2 = (const float*)d_in[6];
    const float* vW0 = (const float*)d_in[7];
    const float* vb0 = (const float*)d_in[8];
    const float* vW1 = (const float*)d_in[9];
    const float* vb1 = (const float*)d_in[10];
    const float* vW2 = (const float*)d_in[11];
    const float* vb2 = (const float*)d_in[12];
    const float* vU0 = (const float*)d_in[13];
    const float* vU1 = (const float*)d_in[14];
    float* out = (float*)d_out;
    (void)in_sizes; (void)n_in; (void)out_size; (void)d_ws; (void)ws_size;

    u16 *xbf, *buf1, *buf2, *z1b, *a2b, *fW0b, *fW1b, *fW2b, *vW0b, *vW1b, *spU0b, *spU0Tb, *vW0Tb, *vW1Tb;
    float *fxb, *gVb, *fb2p, *spU1, *z10, *a20, *ic0, *zacc, *sS, *sVx;
    hipGetSymbolAddress((void**)&xbf,   HIP_SYMBOL(g_xbf));
    hipGetSymbolAddress((void**)&buf1,  HIP_SYMBOL(g_buf1));
    hipGetSymbolAddress((void**)&buf2,  HIP_SYMBOL(g_buf2));
    hipGetSymbolAddress((void**)&z1b,   HIP_SYMBOL(g_z1));
    hipGetSymbolAddress((void**)&a2b,   HIP_SYMBOL(g_a2b));
    hipGetSymbolAddress((void**)&fxb,   HIP_SYMBOL(g_fxb));
    hipGetSymbolAddress((void**)&gVb,   HIP_SYMBOL(g_gVb));
    hipGetSymbolAddress((void**)&fW0b,  HIP_SYMBOL(g_fW0b));
    hipGetSymbolAddress((void**)&fW1b,  HIP_SYMBOL(g_fW1b));
    hipGetSymbolAddress((void**)&fW2b,  HIP_SYMBOL(g_fW2b));
    hipGetSymbolAddress((void**)&vW0b,  HIP_SYMBOL(g_vW0b));
    hipGetSymbolAddress((void**)&vW1b,  HIP_SYMBOL(g_vW1b));
    hipGetSymbolAddress((void**)&spU0b, HIP_SYMBOL(g_spU0b));
    hipGetSymbolAddress((void**)&spU0Tb,HIP_SYMBOL(g_spU0Tb));
    hipGetSymbolAddress((void**)&vW0Tb, HIP_SYMBOL(g_vW0Tb));
    hipGetSymbolAddress((void**)&vW1Tb, HIP_SYMBOL(g_vW1Tb));
    hipGetSymbolAddress((void**)&fb2p,  HIP_SYMBOL(g_fb2p));
    hipGetSymbolAddress((void**)&spU1,  HIP_SYMBOL(g_spU1));
    hipGetSymbolAddress((void**)&z10,   HIP_SYMBOL(g_z10));
    hipGetSymbolAddress((void**)&a20,   HIP_SYMBOL(g_a20));
    hipGetSymbolAddress((void**)&ic0,   HIP_SYMBOL(g_ic0));
    hipGetSymbolAddress((void**)&zacc,  HIP_SYMBOL(g_zacc));
    hipGetSymbolAddress((void**)&sS,    HIP_SYMBOL(g_sS));
    hipGetSymbolAddress((void**)&sVx,   HIP_SYMBOL(g_sVx));

    const dim3 blk(256);

    // ---- one-time precomputes ----
    cast_kernel<0><<<1024, 256, 0, stream>>>(xbf, x, (long)NB * ND);
    cast_kernel<0><<<512, 256, 0, stream>>>(fW0b, fW0, (long)NH * ND);
    cast_kernel<0><<<2048, 256, 0, stream>>>(fW1b, fW1, (long)NH * NH);
    castpad_kernel<<<512, 256, 0, stream>>>(fW2b, fW2, (long)NOUT * NH, (long)ND * NH);
    cast_kernel<0><<<512, 256, 0, stream>>>(vW0b, vW0, (long)NH * ND);
    cast_kernel<0><<<512, 256, 0, stream>>>(vW1b, vW1, (long)NH * ND);
    cast_kernel<2><<<2048, 256, 0, stream>>>(spU0b, vU0, (long)NH * NH);
    transpose_cast_kernel<2><<<dim3(64, 64), dim3(32, 8), 0, stream>>>(spU0Tb, vU0, NH, NH);
    transpose_cast_kernel<0><<<dim3(8, 64), dim3(32, 8), 0, stream>>>(vW0Tb, vW0, NH, ND);
    transpose_cast_kernel<0><<<dim3(8, 64), dim3(32, 8), 0, stream>>>(vW1Tb, vW1, NH, ND);
    ew_softplus_f32<<<8, 256, 0, stream>>>(spU1, vU1, NH);
    ew_rehu_f32<<<8, 256, 0, stream>>>(z10, vb0, NH);
    fb2p_kernel<<<1, 256, 0, stream>>>(fb2p, fb2);
    a20_kernel<<<NH, 256, 0, stream>>>(a20, z10, vU0, vb1);
    icnn0_kernel<<<1, 256, 0, stream>>>(ic0, a20, spU1, vb2);
    clear_kernel<<<64, 256, 0, stream>>>(zacc, NB);

    // ---- fhat MLP ----
    mfma_gemm<0,0><<<2048, blk, 0, stream>>>(nullptr, buf1, xbf, fW0b, ND, ND,
        nullptr, nullptr, fb0, nullptr, nullptr, nullptr, NB, NH, ND, 0);
    mfma_gemm<0,0><<<2048, blk, 0, stream>>>(nullptr, buf2, buf1, fW1b, NH, NH,
        nullptr, nullptr, fb1, nullptr, nullptr, nullptr, NB, NH, NH, 0);
    mfma_gemm<1,0><<<256, blk, 0, stream>>>(fxb, nullptr, buf2, fW2b, NH, NH,
        nullptr, nullptr, fb2p, nullptr, nullptr, nullptr, NB, ND, NH, 0);

    // ---- ICNN forward ----
    mfma_gemm<2,0><<<2048, blk, 0, stream>>>(nullptr, z1b, xbf, vW0b, ND, ND,
        nullptr, nullptr, vb0, nullptr, nullptr, nullptr, NB, NH, ND, 0);
    // a2 = x@vW1^T + vb1 + z1@(spU0/H)^T  ; writes a2 bf16 + per-row zacc
    mfma_gemm<3,1><<<2048, blk, 0, stream>>>(nullptr, a2b, xbf, vW1b, ND, ND,
        z1b, spU0b, vb1, nullptr, zacc, spU1, NB, NH, ND, NH);
    rowfin_ga2_kernel<<<NB, blk, 0, stream>>>(sS, sVx, buf1, x, a2b, zacc, spU1, vW2, vb2, ic0);

    // ---- backward ----
    // g_a1 = (g_a2 @ (spU0/H)) * drehu(a1)  with drehu recovered from z1 bf16
    mfma_gemm<4,0><<<2048, blk, 0, stream>>>(nullptr, buf2, buf1, spU0Tb, NH, NH,
        nullptr, nullptr, nullptr, z1b, nullptr, nullptr, NB, NH, NH, 0);
    gvinit_kernel<<<2048, 256, 0, stream>>>(gVb, sS, vW2, x, (long)NB * ND);
    mfma_gemm<5,0><<<dim3(256, 2), blk, 0, stream>>>(gVb, nullptr, buf1, vW1Tb, NH, NH,
        nullptr, nullptr, nullptr, nullptr, nullptr, nullptr, NB, ND, NH / 2, 0);
    mfma_gemm<5,0><<<dim3(256, 2), blk, 0, stream>>>(gVb, nullptr, buf2, vW0Tb, NH, NH,
        nullptr, nullptr, nullptr, nullptr, nullptr, nullptr, NB, ND, NH / 2, 0);

    final_kernel<<<NB, blk, 0, stream>>>(out, gVb, fxb, sVx);
}

// Round 6
// 1218.525 us; speedup vs baseline: 8.2813x; 1.1337x over previous
//
#include <hip/hip_runtime.h>
#include <hip/hip_bf16.h>
#include <math.h>

#define NB 16384
#define ND 256
#define NH 2048
#define NOUT 255

constexpr float C_ALPHA  = 0.01f;
constexpr float C_REHU_D = 0.01f;
constexpr float C_PSD_D  = 1.0f;
constexpr float C_EPS    = 1e-5f;

typedef unsigned short u16;
typedef short bf16x8 __attribute__((ext_vector_type(8)));
typedef float f32x4 __attribute__((ext_vector_type(4)));

#define GAS __attribute__((address_space(1)))
#define LAS __attribute__((address_space(3)))

// ---- scratch in device globals ----
__device__ u16   g_xbf [(size_t)NB * ND];
__device__ u16   g_buf1[(size_t)NB * NH];   // h1 -> g_a2
__device__ u16   g_buf2[(size_t)NB * NH];   // h2 -> g_a1
__device__ u16   g_z1  [(size_t)NB * NH];   // rehu(a1) bf16
__device__ u16   g_a2b [(size_t)NB * NH];   // a2 bf16
__device__ float g_fxb [(size_t)NB * ND];
__device__ float g_gVb [(size_t)NB * ND];
__device__ u16   g_fW0b[(size_t)NH * ND];
__device__ u16   g_fW1b[(size_t)NH * NH];
__device__ u16   g_fW2b[(size_t)ND * NH];   // padded: row 255 = 0
__device__ u16   g_vW0b[(size_t)NH * ND];
__device__ u16   g_vW1b[(size_t)NH * ND];
__device__ u16   g_spU0b [(size_t)NH * NH];  // softplus(vU0)/NH
__device__ u16   g_spU0Tb[(size_t)NH * NH];  // transpose of above
__device__ u16   g_vW0Tb[(size_t)ND * NH];
__device__ u16   g_vW1Tb[(size_t)ND * NH];
__device__ float g_fb2p[ND];
__device__ float g_spU1[NH];
__device__ float g_z10[NH];
__device__ float g_a20[NH];
__device__ float g_ic0[1];
__device__ float g_zacc[NB];
__device__ float g_sS [NB];
__device__ float g_sVx[NB];

__device__ __forceinline__ float softplus_f(float x) {
    return fmaxf(x, 0.0f) + log1pf(expf(-fabsf(x)));
}
__device__ __forceinline__ float rehu_f(float x, float d) {
    float t = x * fabsf(x) / (2.0f * d);
    t = fminf(fmaxf(t, 0.0f), 0.5f * d);
    return fmaxf(t, x - 0.5f * d);
}
__device__ __forceinline__ float drehu_f(float x, float d) {
    return fminf(fmaxf(x / d, 0.0f), 1.0f);
}
__device__ __forceinline__ u16 f2b(float v) {
    __hip_bfloat16 b = __float2bfloat16(v);
    return *reinterpret_cast<u16*>(&b);
}
__device__ __forceinline__ float b2f(u16 v) {
    unsigned u = ((unsigned)v) << 16;
    return __uint_as_float(u);
}

// valid result on thread 0 only
__device__ __forceinline__ float block_reduce_sum(float v, float* sbuf) {
    #pragma unroll
    for (int off = 32; off > 0; off >>= 1) v += __shfl_down(v, off, 64);
    const int lane = threadIdx.x & 63;
    const int wid  = threadIdx.x >> 6;
    if (lane == 0) sbuf[wid] = v;
    __syncthreads();
    float r = 0.0f;
    if (wid == 0) {
        r = (lane < 4) ? sbuf[lane] : 0.0f;
        r += __shfl_down(r, 2, 64);
        r += __shfl_down(r, 1, 64);
    }
    __syncthreads();
    return r;
}

// ======================= 256^2 8-phase bf16 MFMA GEMM =======================
// Y = A @ B^T (+bias), A [M x K] bf16, B [N x K] bf16 (two K-segments),
// 512 thr / 8 waves (2Mx4N), BK=64, 128KiB LDS dbuf, XOR-swizzled,
// counted vmcnt(4) at phases 4/8, setprio around MFMA clusters.
// EPI 0: Ybf=bf16(relu(v+bias))
// EPI 2: Ybf=bf16(rehu(v+bias,0.01))
// EPI 3: Ybf=bf16(v+bias); zacc[row]+=sum_col rehu(v+bias)*spU1[col]
// EPI 4: Ybf=bf16(v*min(1,sqrt(200*aux)))
template<int EPI>
__global__ __launch_bounds__(512, 2) void gemm8(
    u16* __restrict__ Ybf,
    const u16* __restrict__ A0, int lda0, const u16* __restrict__ B0, int ldb0, int nt0,
    const u16* __restrict__ A1, int lda1, const u16* __restrict__ B1, int ldb1,
    const float* __restrict__ bias, const u16* __restrict__ auxb,
    float* __restrict__ zacc, const float* __restrict__ spU1,
    int N, int nt)
{
    __shared__ u16 smem[65536];           // 128 KiB
    char* lb = (char*)smem;

    const int nwg = gridDim.x;
    const int bid = blockIdx.x;
    const int swz = (bid & 7) * (nwg >> 3) + (bid >> 3);  // XCD swizzle (nwg%8==0)
    const int ntn = N >> 8;
    const int tm = swz / ntn, tn = swz % ntn;
    const int row0 = tm * 256, col0 = tn * 256;

    const int tid  = threadIdx.x;
    const int lane = tid & 63;
    const int wv   = tid >> 6;
    const int wr = wv >> 2, wc = wv & 3;
    const int l15 = lane & 15;
    const int lhi = lane >> 4;

    f32x4 acc[8][4] = {};
    bf16x8 aM[4][2], bLo[2][2], bHi[2][2];

    // stage one half-tile (128x64 bf16) of K-tile kt. h:0=A-lo,1=A-hi,2=B-lo,3=B-hi
    auto stage = [&](int kt, int h) {
        if (kt >= nt) return;
        const u16* base; int ld, k0;
        if (kt < nt0) { base = (h < 2) ? A0 : B0; ld = (h < 2) ? lda0 : ldb0; k0 = kt * 64; }
        else          { base = (h < 2) ? A1 : B1; ld = (h < 2) ? lda1 : ldb1; k0 = (kt - nt0) * 64; }
        const int r0 = ((h < 2) ? row0 : col0) + (h & 1) * 128;
        char* dst = lb + (kt & 1) * 65536 + (h >> 1) * 32768 + (h & 1) * 16384;
        #pragma unroll
        for (int s = 0; s < 2; ++s) {
            const int o  = s * 8192 + wv * 1024 + lane * 16;      // linear dest offset
            const int op = o ^ (((o >> 9) & 3) << 5);             // pre-swizzled source
            const u16* src = base + (size_t)(r0 + (op >> 7)) * ld + k0 + ((op & 127) >> 1);
            __builtin_amdgcn_global_load_lds((const GAS void*)src,
                                             (LAS void*)(dst + s * 8192 + wv * 1024), 16, 0, 0);
        }
    };
    // swizzled LDS fragment read: region byte offset + logical (row, colbyte)
    auto lrd = [&](int off, int lrow, int cb) -> bf16x8 {
        int o = lrow * 128 + cb;
        o ^= ((o >> 9) & 3) << 5;
        return *reinterpret_cast<const bf16x8*>(lb + off + o);
    };

    // ---- prologue: K-tile 0 fully + B-halves of K-tile 1 ----
    stage(0, 0); stage(0, 1); stage(0, 2); stage(0, 3);
    stage(1, 2); stage(1, 3);
    asm volatile("s_waitcnt vmcnt(4)" ::: "memory");
    __builtin_amdgcn_s_barrier();

    const int nit = nt >> 1;
    for (int i = 0; i < nit; ++i) {
        const int t0 = 2 * i, t1 = 2 * i + 1;
        const bool lastit = (i == nit - 1);

        // 4 phases computing K-tile in buffer bufo; stages: phA/B -> (ka,0/1), phC/D -> (kb,2/3)
        auto quad = [&](int bufo, int ka, int kb, bool vmzero) {
            const int aoff = bufo + wr * 16384;
            const int boff = bufo + 32768 + (wc >> 1) * 16384;
            const int brow = (wc & 1) * 64;
            // ---- phase A: read A m0-3 + B n0-1 (12 reads); MFMA m0-3 x n0-1 ----
            #pragma unroll
            for (int m = 0; m < 4; ++m)
                #pragma unroll
                for (int ks = 0; ks < 2; ++ks)
                    aM[m][ks] = lrd(aoff, m * 16 + l15, ks * 64 + lhi * 16);
            #pragma unroll
            for (int n = 0; n < 2; ++n)
                #pragma unroll
                for (int ks = 0; ks < 2; ++ks)
                    bLo[n][ks] = lrd(boff, brow + n * 16 + l15, ks * 64 + lhi * 16);
            stage(ka, 0);
            __builtin_amdgcn_s_barrier();
            asm volatile("s_waitcnt lgkmcnt(0)" ::: "memory");
            __builtin_amdgcn_s_setprio(1);
            #pragma unroll
            for (int m = 0; m < 4; ++m)
                #pragma unroll
                for (int n = 0; n < 2; ++n)
                    #pragma unroll
                    for (int ks = 0; ks < 2; ++ks)
                        acc[m][n] = __builtin_amdgcn_mfma_f32_16x16x32_bf16(aM[m][ks], bLo[n][ks], acc[m][n], 0, 0, 0);
            __builtin_amdgcn_s_setprio(0);
            __builtin_amdgcn_s_barrier();
            // ---- phase B: read B n2-3 (4 reads); MFMA m0-3 x n2-3 ----
            #pragma unroll
            for (int n = 0; n < 2; ++n)
                #pragma unroll
                for (int ks = 0; ks < 2; ++ks)
                    bHi[n][ks] = lrd(boff, brow + (2 + n) * 16 + l15, ks * 64 + lhi * 16);
            stage(ka, 1);
            __builtin_amdgcn_s_barrier();
            asm volatile("s_waitcnt lgkmcnt(0)" ::: "memory");
            __builtin_amdgcn_s_setprio(1);
            #pragma unroll
            for (int m = 0; m < 4; ++m)
                #pragma unroll
                for (int n = 0; n < 2; ++n)
                    #pragma unroll
                    for (int ks = 0; ks < 2; ++ks)
                        acc[m][2 + n] = __builtin_amdgcn_mfma_f32_16x16x32_bf16(aM[m][ks], bHi[n][ks], acc[m][2 + n], 0, 0, 0);
            __builtin_amdgcn_s_setprio(0);
            __builtin_amdgcn_s_barrier();
            // ---- phase C: read A m4-7 (8 reads); MFMA m4-7 x n2-3 ----
            #pragma unroll
            for (int m = 0; m < 4; ++m)
                #pragma unroll
                for (int ks = 0; ks < 2; ++ks)
                    aM[m][ks] = lrd(aoff, (4 + m) * 16 + l15, ks * 64 + lhi * 16);
            stage(kb, 2);
            __builtin_amdgcn_s_barrier();
            asm volatile("s_waitcnt lgkmcnt(0)" ::: "memory");
            __builtin_amdgcn_s_setprio(1);
            #pragma unroll
            for (int m = 0; m < 4; ++m)
                #pragma unroll
                for (int n = 0; n < 2; ++n)
                    #pragma unroll
                    for (int ks = 0; ks < 2; ++ks)
                        acc[4 + m][2 + n] = __builtin_amdgcn_mfma_f32_16x16x32_bf16(aM[m][ks], bHi[n][ks], acc[4 + m][2 + n], 0, 0, 0);
            __builtin_amdgcn_s_setprio(0);
            __builtin_amdgcn_s_barrier();
            // ---- phase D: no reads; MFMA m4-7 x n0-1; counted vmcnt ----
            stage(kb, 3);
            __builtin_amdgcn_s_barrier();
            __builtin_amdgcn_s_setprio(1);
            #pragma unroll
            for (int m = 0; m < 4; ++m)
                #pragma unroll
                for (int n = 0; n < 2; ++n)
                    #pragma unroll
                    for (int ks = 0; ks < 2; ++ks)
                        acc[4 + m][n] = __builtin_amdgcn_mfma_f32_16x16x32_bf16(aM[m][ks], bLo[n][ks], acc[4 + m][n], 0, 0, 0);
            __builtin_amdgcn_s_setprio(0);
            if (vmzero) asm volatile("s_waitcnt vmcnt(0)" ::: "memory");
            else        asm volatile("s_waitcnt vmcnt(4)" ::: "memory");
            __builtin_amdgcn_s_barrier();
        };

        quad(0,     t1,     t0 + 2, lastit);   // phases 1-4: K-tile t0 (buf0)
        quad(65536, t0 + 2, t1 + 2, false);    // phases 5-8: K-tile t1 (buf1)
    }

    // ---- epilogue ----
    #pragma unroll
    for (int m = 0; m < 8; ++m) {
        float rp[4] = {0.f, 0.f, 0.f, 0.f};
        #pragma unroll
        for (int n = 0; n < 4; ++n) {
            const int col = col0 + wc * 64 + n * 16 + l15;
            float bv = 0.0f, spv = 0.0f;
            if (EPI == 0 || EPI == 2 || EPI == 3) bv = bias[col];
            if (EPI == 3) spv = spU1[col];
            #pragma unroll
            for (int q = 0; q < 4; ++q) {
                const int row = row0 + wr * 128 + m * 16 + (lhi << 2) + q;
                const size_t idx = (size_t)row * N + col;
                float v = acc[m][n][q] + bv;
                if (EPI == 0) {
                    Ybf[idx] = f2b(fmaxf(v, 0.0f));
                } else if (EPI == 2) {
                    Ybf[idx] = f2b(rehu_f(v, C_REHU_D));
                } else if (EPI == 3) {
                    Ybf[idx] = f2b(v);
                    rp[q] += rehu_f(v, C_REHU_D) * spv;
                } else { // EPI 4
                    const float z = b2f(auxb[idx]);
                    Ybf[idx] = f2b(v * fminf(sqrtf(200.0f * z), 1.0f));
                }
            }
        }
        if (EPI == 3) {
            #pragma unroll
            for (int q = 0; q < 4; ++q) {
                float s = rp[q];
                s += __shfl_xor(s, 1, 64);
                s += __shfl_xor(s, 2, 64);
                s += __shfl_xor(s, 4, 64);
                s += __shfl_xor(s, 8, 64);
                if (l15 == 0) atomicAdd(&zacc[row0 + wr * 128 + m * 16 + (lhi << 2) + q], s);
            }
        }
    }
}

// ======================= 128^2 MFMA GEMM (split-K atomic path) =======================
// MODE 5: atomicAdd(Y32+idx, A@B^T), koff = blockIdx.y*K
#define BM 128
#define BN 128
#define BK 32

template<int MODE>
__global__ __launch_bounds__(256) void mfma_gemm(
    float* __restrict__ Y32, u16* __restrict__ Ybf,
    const u16* __restrict__ A, const u16* __restrict__ Bm, int lda, int ldb,
    int M, int N, int K)
{
    __shared__ u16 As[BM * BK];
    __shared__ u16 Bs[BN * BK];

    const int ntn = N >> 7;
    const int nwg = gridDim.x;
    const int bid = blockIdx.x;
    const int swz = (bid & 7) * (nwg >> 3) + (bid >> 3);
    const int tm = swz / ntn, tn = swz % ntn;
    const int row0 = tm * BM, col0 = tn * BN;
    const int koff = blockIdx.y * K;

    const int tid  = threadIdx.x;
    const int lane = tid & 63;
    const int wave = tid >> 6;
    const int wr = wave >> 1, wc = wave & 1;

    f32x4 acc[4][4] = {};

    char* AsB = (char*)As + wave * 1024;
    char* BsB = (char*)Bs + wave * 1024;
    const int lr = lane & 15;
    const int lk = (lane >> 4) << 3;

    const u16* Ag = A + (size_t)(row0 + (tid >> 2)) * lda + ((tid & 3) << 3) + koff;
    const u16* Bg = Bm + (size_t)(col0 + (tid >> 2)) * ldb + ((tid & 3) << 3) + koff;

    for (int k0 = 0; k0 < K; k0 += BK) {
        __builtin_amdgcn_global_load_lds((const GAS void*)(Ag + k0), (LAS void*)(AsB), 16, 0, 0);
        __builtin_amdgcn_global_load_lds((const GAS void*)(Ag + (size_t)64 * lda + k0), (LAS void*)(AsB + 4096), 16, 0, 0);
        __builtin_amdgcn_global_load_lds((const GAS void*)(Bg + k0), (LAS void*)(BsB), 16, 0, 0);
        __builtin_amdgcn_global_load_lds((const GAS void*)(Bg + (size_t)64 * ldb + k0), (LAS void*)(BsB + 4096), 16, 0, 0);
        __syncthreads();

        bf16x8 af[4], bfr[4];
        #pragma unroll
        for (int m = 0; m < 4; ++m)
            af[m] = *reinterpret_cast<const bf16x8*>(&As[(wr * 64 + m * 16 + lr) * BK + lk]);
        #pragma unroll
        for (int n = 0; n < 4; ++n)
            bfr[n] = *reinterpret_cast<const bf16x8*>(&Bs[(wc * 64 + n * 16 + lr) * BK + lk]);
        #pragma unroll
        for (int m = 0; m < 4; ++m)
            #pragma unroll
            for (int n = 0; n < 4; ++n)
                acc[m][n] = __builtin_amdgcn_mfma_f32_16x16x32_bf16(af[m], bfr[n], acc[m][n], 0, 0, 0);
        __syncthreads();
    }

    const int rr = (lane >> 4) << 2;
    #pragma unroll
    for (int m = 0; m < 4; ++m) {
        #pragma unroll
        for (int n = 0; n < 4; ++n) {
            const int col = col0 + wc * 64 + n * 16 + lr;
            #pragma unroll
            for (int i = 0; i < 4; ++i) {
                const int row = row0 + wr * 64 + m * 16 + rr + i;
                const size_t idx = (size_t)row * N + col;
                atomicAdd(&Y32[idx], acc[m][n][i]);
                (void)Ybf;
            }
        }
    }
}

// ======================= small helper kernels =======================
template<int OP>  // 0 identity, 2 softplus/NH
__global__ void cast_kernel(u16* __restrict__ dst, const float* __restrict__ src, long n) {
    long i = (long)blockIdx.x * blockDim.x + threadIdx.x;
    const long stride = (long)gridDim.x * blockDim.x;
    for (; i < n; i += stride) {
        float v = src[i];
        if (OP == 2) v = softplus_f(v) * (1.0f / NH);
        dst[i] = f2b(v);
    }
}

__global__ void castpad_kernel(u16* __restrict__ dst, const float* __restrict__ src,
                               long nsrc, long ntot) {
    long i = (long)blockIdx.x * blockDim.x + threadIdx.x;
    const long stride = (long)gridDim.x * blockDim.x;
    for (; i < ntot; i += stride) dst[i] = (i < nsrc) ? f2b(src[i]) : (u16)0;
}

template<int OP>  // dst[c*R + r] = op(src[r*C + c]); grid (C/32, R/32), block (32,8)
__global__ __launch_bounds__(256) void transpose_cast_kernel(
    u16* __restrict__ dst, const float* __restrict__ src, int R, int C)
{
    __shared__ float t[32][33];
    const int c0 = blockIdx.x * 32, r0 = blockIdx.y * 32;
    for (int i = threadIdx.y; i < 32; i += 8)
        t[i][threadIdx.x] = src[(size_t)(r0 + i) * C + c0 + threadIdx.x];
    __syncthreads();
    for (int i = threadIdx.y; i < 32; i += 8) {
        float v = t[threadIdx.x][i];
        if (OP == 2) v = softplus_f(v) * (1.0f / NH);
        dst[(size_t)(c0 + i) * R + r0 + threadIdx.x] = f2b(v);
    }
}

__global__ void ew_softplus_f32(float* __restrict__ dst, const float* __restrict__ src, long n) {
    long i = (long)blockIdx.x * blockDim.x + threadIdx.x;
    const long stride = (long)gridDim.x * blockDim.x;
    for (; i < n; i += stride) dst[i] = softplus_f(src[i]);
}

__global__ void ew_rehu_f32(float* __restrict__ dst, const float* __restrict__ src, long n) {
    long i = (long)blockIdx.x * blockDim.x + threadIdx.x;
    const long stride = (long)gridDim.x * blockDim.x;
    for (; i < n; i += stride) dst[i] = rehu_f(src[i], C_REHU_D);
}

__global__ void clear_kernel(float* __restrict__ dst, long n) {
    long i = (long)blockIdx.x * blockDim.x + threadIdx.x;
    const long stride = (long)gridDim.x * blockDim.x;
    for (; i < n; i += stride) dst[i] = 0.0f;
}

__global__ void fxinit_kernel(float* __restrict__ fxb, const float* __restrict__ fb2p) {
    long i = (long)blockIdx.x * blockDim.x + threadIdx.x;
    const long n = (long)NB * ND;
    const long stride = (long)gridDim.x * blockDim.x;
    for (; i < n; i += stride) fxb[i] = fb2p[i & (ND - 1)];
}

__global__ void fb2p_kernel(float* __restrict__ dst, const float* __restrict__ fb2) {
    const int c = threadIdx.x;
    dst[c] = (c < NOUT) ? fb2[c] : 1.0f;
}

// a2_0[j] = vb1[j] + (1/H) * sum_k z1_0[k] * softplus(vU0[j,k])
__global__ __launch_bounds__(256) void a20_kernel(
    float* __restrict__ a20, const float* __restrict__ z10,
    const float* __restrict__ vU0, const float* __restrict__ vb1)
{
    __shared__ float sbuf[4];
    const int j = blockIdx.x;
    float sum = 0.0f;
    const float* row = vU0 + (size_t)j * NH;
    for (int k = threadIdx.x; k < NH; k += 256) sum += z10[k] * softplus_f(row[k]);
    sum = block_reduce_sum(sum, sbuf);
    if (threadIdx.x == 0) a20[j] = vb1[j] + sum * (1.0f / NH);
}

// icnn0 = vb2 + sum_j rehu(a2_0[j]) * spU1[j]   (vU1.shape[0] == 1 -> no /H)
__global__ __launch_bounds__(256) void icnn0_kernel(
    float* __restrict__ ic0, const float* __restrict__ a20,
    const float* __restrict__ spU1, const float* __restrict__ vb2)
{
    __shared__ float sbuf[4];
    float sum = 0.0f;
    for (int j = threadIdx.x; j < NH; j += 256) sum += rehu_f(a20[j], C_REHU_D) * spU1[j];
    sum = block_reduce_sum(sum, sbuf);
    if (threadIdx.x == 0) ic0[0] = vb2[0] + sum;
}

// per row b: d1 = x.vW2, d2 = ||x||^2; diff = d1 + vb2 + zacc[b] - ic0
// sS = clamp(diff,0,1); sVx = rehu(diff,1) + eps*d2; ga2[b,:] = sS*spU1*drehu(a2)
__global__ __launch_bounds__(256) void rowfin_ga2_kernel(
    float* __restrict__ sS, float* __restrict__ sVx, u16* __restrict__ ga2,
    const float* __restrict__ x, const u16* __restrict__ a2b,
    const float* __restrict__ zacc, const float* __restrict__ spU1,
    const float* __restrict__ vW2, const float* __restrict__ vb2,
    const float* __restrict__ ic0)
{
    __shared__ float sbuf[4];
    __shared__ float ssh;
    const int b = blockIdx.x;
    const int t = threadIdx.x;
    const float xv = x[(size_t)b * ND + t];
    const float d1 = block_reduce_sum(xv * vW2[t], sbuf);
    const float d2 = block_reduce_sum(xv * xv, sbuf);
    if (t == 0) {
        const float diff = d1 + vb2[0] + zacc[b] - ic0[0];
        const float s = fminf(fmaxf(diff / C_PSD_D, 0.0f), 1.0f);
        sS[b]  = s;
        sVx[b] = rehu_f(diff, C_PSD_D) + C_EPS * d2;
        ssh = s;
    }
    __syncthreads();
    const float s = ssh;
    const bf16x8 av = *reinterpret_cast<const bf16x8*>(a2b + (size_t)b * NH + t * 8);
    bf16x8 ov;
    #pragma unroll
    for (int j = 0; j < 8; ++j) {
        const float a2v = b2f((u16)av[j]);
        const float g = s * spU1[t * 8 + j] * drehu_f(a2v, C_REHU_D);
        ov[j] = (short)f2b(g);
    }
    *reinterpret_cast<bf16x8*>(ga2 + (size_t)b * NH + t * 8) = ov;
}

// gV[b,c] = s[b]*vW2[c] + 2*eps*x[b,c]
__global__ void gvinit_kernel(float* __restrict__ gV, const float* __restrict__ sS,
                              const float* __restrict__ vW2, const float* __restrict__ x,
                              long n) {
    long i = (long)blockIdx.x * blockDim.x + threadIdx.x;
    const long stride = (long)gridDim.x * blockDim.x;
    for (; i < n; i += stride) {
        const int b = (int)(i >> 8);
        const int c = (int)(i & (ND - 1));
        gV[i] = sS[b] * vW2[c] + 2.0f * C_EPS * x[i];
    }
}

__global__ __launch_bounds__(256) void final_kernel(
    float* __restrict__ out, const float* __restrict__ gV,
    const float* __restrict__ fx, const float* __restrict__ sVx)
{
    __shared__ float sbuf[4];
    __shared__ float scoef;
    const int b = blockIdx.x;
    const int t = threadIdx.x;
    const float g = gV[(size_t)b * ND + t];
    const float f = fx[(size_t)b * ND + t];
    const float gf = block_reduce_sum(g * f, sbuf);
    const float gg = block_reduce_sum(g * g, sbuf);
    if (t == 0) {
        const float num = fmaxf(gf + C_ALPHA * sVx[b], 0.0f);
        scoef = num / gg;
    }
    __syncthreads();
    const float coef = scoef;
    if (t < NOUT) out[(size_t)b * NOUT + t] = f - g * coef;
}

extern "C" void kernel_launch(void* const* d_in, const int* in_sizes, int n_in,
                              void* d_out, int out_size, void* d_ws, size_t ws_size,
                              hipStream_t stream)
{
    const float* x   = (const float*)d_in[0];
    const float* fW0 = (const float*)d_in[1];
    const float* fb0 = (const float*)d_in[2];
    const float* fW1 = (const float*)d_in[3];
    const float* fb1 = (const float*)d_in[4];
    const float* fW2 = (const float*)d_in[5];
    const float* fb2 = (const float*)d_in[6];
    const float* vW0 = (const float*)d_in[7];
    const float* vb0 = (const float*)d_in[8];
    const float* vW1 = (const float*)d_in[9];
    const float* vb1 = (const float*)d_in[10];
    const float* vW2 = (const float*)d_in[11];
    const float* vb2 = (const float*)d_in[12];
    const float* vU0 = (const float*)d_in[13];
    const float* vU1 = (const float*)d_in[14];
    float* out = (float*)d_out;
    (void)in_sizes; (void)n_in; (void)out_size; (void)d_ws; (void)ws_size;

    u16 *xbf, *buf1, *buf2, *z1b, *a2b, *fW0b, *fW1b, *fW2b, *vW0b, *vW1b, *spU0b, *spU0Tb, *vW0Tb, *vW1Tb;
    float *fxb, *gVb, *fb2p, *spU1, *z10, *a20, *ic0, *zacc, *sS, *sVx;
    hipGetSymbolAddress((void**)&xbf,   HIP_SYMBOL(g_xbf));
    hipGetSymbolAddress((void**)&buf1,  HIP_SYMBOL(g_buf1));
    hipGetSymbolAddress((void**)&buf2,  HIP_SYMBOL(g_buf2));
    hipGetSymbolAddress((void**)&z1b,   HIP_SYMBOL(g_z1));
    hipGetSymbolAddress((void**)&a2b,   HIP_SYMBOL(g_a2b));
    hipGetSymbolAddress((void**)&fxb,   HIP_SYMBOL(g_fxb));
    hipGetSymbolAddress((void**)&gVb,   HIP_SYMBOL(g_gVb));
    hipGetSymbolAddress((void**)&fW0b,  HIP_SYMBOL(g_fW0b));
    hipGetSymbolAddress((void**)&fW1b,  HIP_SYMBOL(g_fW1b));
    hipGetSymbolAddress((void**)&fW2b,  HIP_SYMBOL(g_fW2b));
    hipGetSymbolAddress((void**)&vW0b,  HIP_SYMBOL(g_vW0b));
    hipGetSymbolAddress((void**)&vW1b,  HIP_SYMBOL(g_vW1b));
    hipGetSymbolAddress((void**)&spU0b, HIP_SYMBOL(g_spU0b));
    hipGetSymbolAddress((void**)&spU0Tb,HIP_SYMBOL(g_spU0Tb));
    hipGetSymbolAddress((void**)&vW0Tb, HIP_SYMBOL(g_vW0Tb));
    hipGetSymbolAddress((void**)&vW1Tb, HIP_SYMBOL(g_vW1Tb));
    hipGetSymbolAddress((void**)&fb2p,  HIP_SYMBOL(g_fb2p));
    hipGetSymbolAddress((void**)&spU1,  HIP_SYMBOL(g_spU1));
    hipGetSymbolAddress((void**)&z10,   HIP_SYMBOL(g_z10));
    hipGetSymbolAddress((void**)&a20,   HIP_SYMBOL(g_a20));
    hipGetSymbolAddress((void**)&ic0,   HIP_SYMBOL(g_ic0));
    hipGetSymbolAddress((void**)&zacc,  HIP_SYMBOL(g_zacc));
    hipGetSymbolAddress((void**)&sS,    HIP_SYMBOL(g_sS));
    hipGetSymbolAddress((void**)&sVx,   HIP_SYMBOL(g_sVx));

    // ---- one-time precomputes ----
    cast_kernel<0><<<1024, 256, 0, stream>>>(xbf, x, (long)NB * ND);
    cast_kernel<0><<<512, 256, 0, stream>>>(fW0b, fW0, (long)NH * ND);
    cast_kernel<0><<<2048, 256, 0, stream>>>(fW1b, fW1, (long)NH * NH);
    castpad_kernel<<<512, 256, 0, stream>>>(fW2b, fW2, (long)NOUT * NH, (long)ND * NH);
    cast_kernel<0><<<512, 256, 0, stream>>>(vW0b, vW0, (long)NH * ND);
    cast_kernel<0><<<512, 256, 0, stream>>>(vW1b, vW1, (long)NH * ND);
    cast_kernel<2><<<2048, 256, 0, stream>>>(spU0b, vU0, (long)NH * NH);
    transpose_cast_kernel<2><<<dim3(64, 64), dim3(32, 8), 0, stream>>>(spU0Tb, vU0, NH, NH);
    transpose_cast_kernel<0><<<dim3(8, 64), dim3(32, 8), 0, stream>>>(vW0Tb, vW0, NH, ND);
    transpose_cast_kernel<0><<<dim3(8, 64), dim3(32, 8), 0, stream>>>(vW1Tb, vW1, NH, ND);
    ew_softplus_f32<<<8, 256, 0, stream>>>(spU1, vU1, NH);
    ew_rehu_f32<<<8, 256, 0, stream>>>(z10, vb0, NH);
    fb2p_kernel<<<1, 256, 0, stream>>>(fb2p, fb2);
    a20_kernel<<<NH, 256, 0, stream>>>(a20, z10, vU0, vb1);
    icnn0_kernel<<<1, 256, 0, stream>>>(ic0, a20, spU1, vb2);
    clear_kernel<<<64, 256, 0, stream>>>(zacc, NB);

    // ---- fhat MLP ----
    gemm8<0><<<512, 512, 0, stream>>>(buf1, xbf, ND, fW0b, ND, 4,
        nullptr, 0, nullptr, 0, fb0, nullptr, nullptr, nullptr, NH, 4);
    gemm8<0><<<512, 512, 0, stream>>>(buf2, buf1, NH, fW1b, NH, 32,
        nullptr, 0, nullptr, 0, fb1, nullptr, nullptr, nullptr, NH, 32);
    fxinit_kernel<<<2048, 256, 0, stream>>>(fxb, fb2p);
    mfma_gemm<5><<<dim3(256, 4), 256, 0, stream>>>(fxb, nullptr, buf2, fW2b, NH, NH, NB, ND, NH / 4);

    // ---- ICNN forward ----
    gemm8<2><<<512, 512, 0, stream>>>(z1b, xbf, ND, vW0b, ND, 4,
        nullptr, 0, nullptr, 0, vb0, nullptr, nullptr, nullptr, NH, 4);
    // a2 = x@vW1^T + vb1 + z1@(spU0/H)^T  (two K-segments) + per-row zacc
    gemm8<3><<<512, 512, 0, stream>>>(a2b, xbf, ND, vW1b, ND, 4,
        z1b, NH, spU0b, NH, vb1, nullptr, zacc, spU1, NH, 36);
    rowfin_ga2_kernel<<<NB, 256, 0, stream>>>(sS, sVx, buf1, x, a2b, zacc, spU1, vW2, vb2, ic0);

    // ---- backward ----
    // g_a1 = (g_a2 @ (spU0/H)) * drehu(a1)  with drehu recovered from z1 bf16
    gemm8<4><<<512, 512, 0, stream>>>(buf2, buf1, NH, spU0Tb, NH, 32,
        nullptr, 0, nullptr, 0, nullptr, z1b, nullptr, nullptr, NH, 32);
    gvinit_kernel<<<2048, 256, 0, stream>>>(gVb, sS, vW2, x, (long)NB * ND);
    mfma_gemm<5><<<dim3(256, 4), 256, 0, stream>>>(gVb, nullptr, buf1, vW1Tb, NH, NH, NB, ND, NH / 4);
    mfma_gemm<5><<<dim3(256, 4), 256, 0, stream>>>(gVb, nullptr, buf2, vW0Tb, NH, NH, NB, ND, NH / 4);

    final_kernel<<<NB, 256, 0, stream>>>(out, gVb, fxb, sVx);
}

// Round 11
// 895.317 us; speedup vs baseline: 11.2709x; 1.3610x over previous
//
#include <hip/hip_runtime.h>
#include <hip/hip_bf16.h>
#include <math.h>

#define NB 16384
#define ND 256
#define NH 2048
#define NOUT 255

constexpr float C_ALPHA  = 0.01f;
constexpr float C_REHU_D = 0.01f;
constexpr float C_PSD_D  = 1.0f;
constexpr float C_EPS    = 1e-5f;

typedef unsigned short u16;
typedef short bf16x8 __attribute__((ext_vector_type(8)));
typedef float f32x4 __attribute__((ext_vector_type(4)));

#define GAS __attribute__((address_space(1)))
#define LAS __attribute__((address_space(3)))

// ---- scratch in device globals ----
__device__ u16   g_xbf [(size_t)NB * ND];
__device__ u16   g_buf1[(size_t)NB * NH];   // h1 -> g_a2
__device__ u16   g_buf2[(size_t)NB * NH];   // h2 -> g_a1
__device__ u16   g_z1  [(size_t)NB * NH];   // rehu(a1) bf16
__device__ u16   g_a2b [(size_t)NB * NH];   // a2 bf16
__device__ float g_fxb [(size_t)NB * ND];
__device__ float g_gVb [(size_t)NB * ND];
__device__ u16   g_fW0b[(size_t)NH * ND];
__device__ u16   g_fW1b[(size_t)NH * NH];
__device__ u16   g_fW2b[(size_t)ND * NH];   // padded: row 255 = 0
__device__ u16   g_vW0b[(size_t)NH * ND];
__device__ u16   g_vW1b[(size_t)NH * ND];
__device__ u16   g_spU0b [(size_t)NH * NH];  // softplus(vU0)/NH
__device__ u16   g_spU0Tb[(size_t)NH * NH];  // transpose of above
__device__ u16   g_vW0Tb[(size_t)ND * NH];
__device__ u16   g_vW1Tb[(size_t)ND * NH];
__device__ float g_fb2p[ND];
__device__ float g_spU1[NH];
__device__ float g_z10[NH];
__device__ float g_a20[NH];
__device__ float g_ic0[1];
__device__ float g_zacc[NB];
__device__ float g_sS [NB];
__device__ float g_sVx[NB];

__device__ __forceinline__ float softplus_f(float x) {
    return fmaxf(x, 0.0f) + log1pf(expf(-fabsf(x)));
}
__device__ __forceinline__ float rehu_f(float x, float d) {
    float t = x * fabsf(x) / (2.0f * d);
    t = fminf(fmaxf(t, 0.0f), 0.5f * d);
    return fmaxf(t, x - 0.5f * d);
}
__device__ __forceinline__ float drehu_f(float x, float d) {
    return fminf(fmaxf(x / d, 0.0f), 1.0f);
}
__device__ __forceinline__ u16 f2b(float v) {
    __hip_bfloat16 b = __float2bfloat16(v);
    return *reinterpret_cast<u16*>(&b);
}
__device__ __forceinline__ float b2f(u16 v) {
    unsigned u = ((unsigned)v) << 16;
    return __uint_as_float(u);
}

// valid result on thread 0 only
__device__ __forceinline__ float block_reduce_sum(float v, float* sbuf) {
    #pragma unroll
    for (int off = 32; off > 0; off >>= 1) v += __shfl_down(v, off, 64);
    const int lane = threadIdx.x & 63;
    const int wid  = threadIdx.x >> 6;
    if (lane == 0) sbuf[wid] = v;
    __syncthreads();
    float r = 0.0f;
    if (wid == 0) {
        r = (lane < 4) ? sbuf[lane] : 0.0f;
        r += __shfl_down(r, 2, 64);
        r += __shfl_down(r, 1, 64);
    }
    __syncthreads();
    return r;
}

// ======================= 256^2 8-phase bf16 MFMA GEMM =======================
// Y = A @ B^T (+bias), A [M x K] bf16, B [N x K] bf16 (two K-segments),
// 512 thr / 8 waves (2Mx4N), BK=64, 128KiB LDS dbuf, 3-bit XOR swizzle,
// counted vmcnt(4) at phases 4/8, setprio around MFMA clusters.
// EPI 0: Ybf=bf16(relu(v+bias))
// EPI 2: Ybf=bf16(rehu(v+bias,0.01))
// EPI 3: Ybf=bf16(v+bias); zacc[row]+=sum_col rehu(v+bias)*spU1[col]
// EPI 4: Ybf=bf16(v*min(1,sqrt(200*aux)))
template<int EPI>
__global__ __launch_bounds__(512, 2) void gemm8(
    u16* __restrict__ Ybf,
    const u16* __restrict__ A0, int lda0, const u16* __restrict__ B0, int ldb0, int nt0,
    const u16* __restrict__ A1, int lda1, const u16* __restrict__ B1, int ldb1,
    const float* __restrict__ bias, const u16* __restrict__ auxb,
    float* __restrict__ zacc, const float* __restrict__ spU1,
    int N, int nt)
{
    __shared__ u16 smem[65536];           // 128 KiB
    char* lb = (char*)smem;

    const int nwg = gridDim.x;
    const int bid = blockIdx.x;
    const int swz = (bid & 7) * (nwg >> 3) + (bid >> 3);  // XCD swizzle (nwg%8==0)
    const int ntn = N >> 8;
    const int tm = swz / ntn, tn = swz % ntn;
    const int row0 = tm * 256, col0 = tn * 256;

    const int tid  = threadIdx.x;
    const int lane = tid & 63;
    const int wv   = tid >> 6;
    const int wr = wv >> 2, wc = wv & 3;
    const int l15 = lane & 15;
    const int lhi = lane >> 4;

    f32x4 acc[8][4] = {};
    bf16x8 aM[4][2], bLo[2][2], bHi[2][2];

    // stage one half-tile (128x64 bf16) of K-tile kt. h:0=A-lo,1=A-hi,2=B-lo,3=B-hi
    auto stage = [&](int kt, int h) {
        if (kt >= nt) return;
        const u16* base; int ld, k0;
        if (kt < nt0) { base = (h < 2) ? A0 : B0; ld = (h < 2) ? lda0 : ldb0; k0 = kt * 64; }
        else          { base = (h < 2) ? A1 : B1; ld = (h < 2) ? lda1 : ldb1; k0 = (kt - nt0) * 64; }
        const int r0 = ((h < 2) ? row0 : col0) + (h & 1) * 128;
        char* dst = lb + (kt & 1) * 65536 + (h >> 1) * 32768 + (h & 1) * 16384;
        #pragma unroll
        for (int s = 0; s < 2; ++s) {
            const int o  = s * 8192 + wv * 1024 + lane * 16;      // linear dest offset
            const int op = o ^ (((o >> 7) & 7) << 4);             // 3-bit pre-swizzled source
            const u16* src = base + (size_t)(r0 + (op >> 7)) * ld + k0 + ((op & 127) >> 1);
            __builtin_amdgcn_global_load_lds((const GAS void*)src,
                                             (LAS void*)(dst + s * 8192 + wv * 1024), 16, 0, 0);
        }
    };
    // swizzled LDS fragment read: region byte offset + logical (row, colbyte)
    auto lrd = [&](int off, int lrow, int cb) -> bf16x8 {
        int o = lrow * 128 + cb;
        o ^= ((o >> 7) & 7) << 4;
        return *reinterpret_cast<const bf16x8*>(lb + off + o);
    };

    // ---- prologue: K-tile 0 fully + B-halves of K-tile 1 ----
    stage(0, 0); stage(0, 1); stage(0, 2); stage(0, 3);
    stage(1, 2); stage(1, 3);
    asm volatile("s_waitcnt vmcnt(4)" ::: "memory");
    __builtin_amdgcn_s_barrier();

    const int nit = nt >> 1;
    for (int i = 0; i < nit; ++i) {
        const int t0 = 2 * i, t1 = 2 * i + 1;
        const bool lastit = (i == nit - 1);

        // 4 phases computing K-tile in buffer bufo; stages: phA/B -> (ka,0/1), phC/D -> (kb,2/3)
        auto quad = [&](int bufo, int ka, int kb, bool vmzero) {
            const int aoff = bufo + wr * 16384;
            const int boff = bufo + 32768 + (wc >> 1) * 16384;
            const int brow = (wc & 1) * 64;
            // ---- phase A: read A m0-3 + B n0-1 (12 reads); MFMA m0-3 x n0-1 ----
            #pragma unroll
            for (int m = 0; m < 4; ++m)
                #pragma unroll
                for (int ks = 0; ks < 2; ++ks)
                    aM[m][ks] = lrd(aoff, m * 16 + l15, ks * 64 + lhi * 16);
            #pragma unroll
            for (int n = 0; n < 2; ++n)
                #pragma unroll
                for (int ks = 0; ks < 2; ++ks)
                    bLo[n][ks] = lrd(boff, brow + n * 16 + l15, ks * 64 + lhi * 16);
            stage(ka, 0);
            __builtin_amdgcn_s_barrier();
            asm volatile("s_waitcnt lgkmcnt(0)" ::: "memory");
            __builtin_amdgcn_s_setprio(1);
            #pragma unroll
            for (int m = 0; m < 4; ++m)
                #pragma unroll
                for (int n = 0; n < 2; ++n)
                    #pragma unroll
                    for (int ks = 0; ks < 2; ++ks)
                        acc[m][n] = __builtin_amdgcn_mfma_f32_16x16x32_bf16(aM[m][ks], bLo[n][ks], acc[m][n], 0, 0, 0);
            __builtin_amdgcn_s_setprio(0);
            __builtin_amdgcn_s_barrier();
            // ---- phase B: read B n2-3 (4 reads); MFMA m0-3 x n2-3 ----
            #pragma unroll
            for (int n = 0; n < 2; ++n)
                #pragma unroll
                for (int ks = 0; ks < 2; ++ks)
                    bHi[n][ks] = lrd(boff, brow + (2 + n) * 16 + l15, ks * 64 + lhi * 16);
            stage(ka, 1);
            __builtin_amdgcn_s_barrier();
            asm volatile("s_waitcnt lgkmcnt(0)" ::: "memory");
            __builtin_amdgcn_s_setprio(1);
            #pragma unroll
            for (int m = 0; m < 4; ++m)
                #pragma unroll
                for (int n = 0; n < 2; ++n)
                    #pragma unroll
                    for (int ks = 0; ks < 2; ++ks)
                        acc[m][2 + n] = __builtin_amdgcn_mfma_f32_16x16x32_bf16(aM[m][ks], bHi[n][ks], acc[m][2 + n], 0, 0, 0);
            __builtin_amdgcn_s_setprio(0);
            __builtin_amdgcn_s_barrier();
            // ---- phase C: read A m4-7 (8 reads); MFMA m4-7 x n2-3 ----
            #pragma unroll
            for (int m = 0; m < 4; ++m)
                #pragma unroll
                for (int ks = 0; ks < 2; ++ks)
                    aM[m][ks] = lrd(aoff, (4 + m) * 16 + l15, ks * 64 + lhi * 16);
            stage(kb, 2);
            __builtin_amdgcn_s_barrier();
            asm volatile("s_waitcnt lgkmcnt(0)" ::: "memory");
            __builtin_amdgcn_s_setprio(1);
            #pragma unroll
            for (int m = 0; m < 4; ++m)
                #pragma unroll
                for (int n = 0; n < 2; ++n)
                    #pragma unroll
                    for (int ks = 0; ks < 2; ++ks)
                        acc[4 + m][2 + n] = __builtin_amdgcn_mfma_f32_16x16x32_bf16(aM[m][ks], bHi[n][ks], acc[4 + m][2 + n], 0, 0, 0);
            __builtin_amdgcn_s_setprio(0);
            __builtin_amdgcn_s_barrier();
            // ---- phase D: no reads; MFMA m4-7 x n0-1; counted vmcnt ----
            stage(kb, 3);
            __builtin_amdgcn_s_barrier();
            __builtin_amdgcn_s_setprio(1);
            #pragma unroll
            for (int m = 0; m < 4; ++m)
                #pragma unroll
                for (int n = 0; n < 2; ++n)
                    #pragma unroll
                    for (int ks = 0; ks < 2; ++ks)
                        acc[4 + m][n] = __builtin_amdgcn_mfma_f32_16x16x32_bf16(aM[m][ks], bLo[n][ks], acc[4 + m][n], 0, 0, 0);
            __builtin_amdgcn_s_setprio(0);
            if (vmzero) asm volatile("s_waitcnt vmcnt(0)" ::: "memory");
            else        asm volatile("s_waitcnt vmcnt(4)" ::: "memory");
            __builtin_amdgcn_s_barrier();
        };

        quad(0,     t1,     t0 + 2, lastit);   // phases 1-4: K-tile t0 (buf0)
        quad(65536, t0 + 2, t1 + 2, false);    // phases 5-8: K-tile t1 (buf1)
    }

    // ---- epilogue ----
    #pragma unroll
    for (int m = 0; m < 8; ++m) {
        float rp[4] = {0.f, 0.f, 0.f, 0.f};
        #pragma unroll
        for (int n = 0; n < 4; ++n) {
            const int col = col0 + wc * 64 + n * 16 + l15;
            float bv = 0.0f, spv = 0.0f;
            if (EPI == 0 || EPI == 2 || EPI == 3) bv = bias[col];
            if (EPI == 3) spv = spU1[col];
            #pragma unroll
            for (int q = 0; q < 4; ++q) {
                const int row = row0 + wr * 128 + m * 16 + (lhi << 2) + q;
                const size_t idx = (size_t)row * N + col;
                float v = acc[m][n][q] + bv;
                if (EPI == 0) {
                    Ybf[idx] = f2b(fmaxf(v, 0.0f));
                } else if (EPI == 2) {
                    Ybf[idx] = f2b(rehu_f(v, C_REHU_D));
                } else if (EPI == 3) {
                    Ybf[idx] = f2b(v);
                    rp[q] += rehu_f(v, C_REHU_D) * spv;
                } else { // EPI 4
                    const float z = b2f(auxb[idx]);
                    Ybf[idx] = f2b(v * fminf(sqrtf(200.0f * z), 1.0f));
                }
            }
        }
        if (EPI == 3) {
            #pragma unroll
            for (int q = 0; q < 4; ++q) {
                float s = rp[q];
                s += __shfl_xor(s, 1, 64);
                s += __shfl_xor(s, 2, 64);
                s += __shfl_xor(s, 4, 64);
                s += __shfl_xor(s, 8, 64);
                if (l15 == 0) atomicAdd(&zacc[row0 + wr * 128 + m * 16 + (lhi << 2) + q], s);
            }
        }
    }
}

// ======================= 128^2 MFMA GEMM (atomic fp32 output) =======================
// SEG==0: split-K, koff = blockIdx.y*K, operands (A,B)
// SEG==1: blockIdx.y selects segment: 0 -> (A,B), 1 -> (A2,B2); full K each
#define BM 128
#define BN 128
#define BK 32

template<int SEG>
__global__ __launch_bounds__(256) void mfma_gemm(
    float* __restrict__ Y32,
    const u16* __restrict__ A, const u16* __restrict__ Bm, int lda, int ldb,
    const u16* __restrict__ A2, const u16* __restrict__ B2,
    int M, int N, int K)
{
    __shared__ u16 As[BM * BK];
    __shared__ u16 Bs[BN * BK];

    const int ntn = N >> 7;
    const int nwg = gridDim.x;
    const int bid = blockIdx.x;
    const int swz = (bid & 7) * (nwg >> 3) + (bid >> 3);
    const int tm = swz / ntn, tn = swz % ntn;
    const int row0 = tm * BM, col0 = tn * BN;

    const u16* Abase = (SEG && blockIdx.y) ? A2 : A;
    const u16* Bbase = (SEG && blockIdx.y) ? B2 : Bm;
    const int koff = SEG ? 0 : blockIdx.y * K;

    const int tid  = threadIdx.x;
    const int lane = tid & 63;
    const int wave = tid >> 6;
    const int wr = wave >> 1, wc = wave & 1;

    f32x4 acc[4][4] = {};

    char* AsB = (char*)As + wave * 1024;
    char* BsB = (char*)Bs + wave * 1024;
    const int lr = lane & 15;
    const int lk = (lane >> 4) << 3;

    const u16* Ag = Abase + (size_t)(row0 + (tid >> 2)) * lda + ((tid & 3) << 3) + koff;
    const u16* Bg = Bbase + (size_t)(col0 + (tid >> 2)) * ldb + ((tid & 3) << 3) + koff;

    for (int k0 = 0; k0 < K; k0 += BK) {
        __builtin_amdgcn_global_load_lds((const GAS void*)(Ag + k0), (LAS void*)(AsB), 16, 0, 0);
        __builtin_amdgcn_global_load_lds((const GAS void*)(Ag + (size_t)64 * lda + k0), (LAS void*)(AsB + 4096), 16, 0, 0);
        __builtin_amdgcn_global_load_lds((const GAS void*)(Bg + k0), (LAS void*)(BsB), 16, 0, 0);
        __builtin_amdgcn_global_load_lds((const GAS void*)(Bg + (size_t)64 * ldb + k0), (LAS void*)(BsB + 4096), 16, 0, 0);
        __syncthreads();

        bf16x8 af[4], bfr[4];
        #pragma unroll
        for (int m = 0; m < 4; ++m)
            af[m] = *reinterpret_cast<const bf16x8*>(&As[(wr * 64 + m * 16 + lr) * BK + lk]);
        #pragma unroll
        for (int n = 0; n < 4; ++n)
            bfr[n] = *reinterpret_cast<const bf16x8*>(&Bs[(wc * 64 + n * 16 + lr) * BK + lk]);
        #pragma unroll
        for (int m = 0; m < 4; ++m)
            #pragma unroll
            for (int n = 0; n < 4; ++n)
                acc[m][n] = __builtin_amdgcn_mfma_f32_16x16x32_bf16(af[m], bfr[n], acc[m][n], 0, 0, 0);
        __syncthreads();
    }

    const int rr = (lane >> 4) << 2;
    #pragma unroll
    for (int m = 0; m < 4; ++m) {
        #pragma unroll
        for (int n = 0; n < 4; ++n) {
            const int col = col0 + wc * 64 + n * 16 + lr;
            #pragma unroll
            for (int i = 0; i < 4; ++i) {
                const int row = row0 + wr * 64 + m * 16 + rr + i;
                atomicAdd(&Y32[(size_t)row * N + col], acc[m][n][i]);
            }
        }
    }
}

// ======================= small helper kernels =======================
template<int OP>  // 0 identity, 2 softplus/NH
__global__ void cast_kernel(u16* __restrict__ dst, const float* __restrict__ src, long n) {
    long i = (long)blockIdx.x * blockDim.x + threadIdx.x;
    const long stride = (long)gridDim.x * blockDim.x;
    for (; i < n; i += stride) {
        float v = src[i];
        if (OP == 2) v = softplus_f(v) * (1.0f / NH);
        dst[i] = f2b(v);
    }
}

__global__ void castpad_kernel(u16* __restrict__ dst, const float* __restrict__ src,
                               long nsrc, long ntot) {
    long i = (long)blockIdx.x * blockDim.x + threadIdx.x;
    const long stride = (long)gridDim.x * blockDim.x;
    for (; i < ntot; i += stride) dst[i] = (i < nsrc) ? f2b(src[i]) : (u16)0;
}

template<int OP>  // dst[c*R + r] = op(src[r*C + c]); grid (C/32, R/32), block (32,8)
__global__ __launch_bounds__(256) void transpose_cast_kernel(
    u16* __restrict__ dst, const float* __restrict__ src, int R, int C)
{
    __shared__ float t[32][33];
    const int c0 = blockIdx.x * 32, r0 = blockIdx.y * 32;
    for (int i = threadIdx.y; i < 32; i += 8)
        t[i][threadIdx.x] = src[(size_t)(r0 + i) * C + c0 + threadIdx.x];
    __syncthreads();
    for (int i = threadIdx.y; i < 32; i += 8) {
        float v = t[threadIdx.x][i];
        if (OP == 2) v = softplus_f(v) * (1.0f / NH);
        dst[(size_t)(c0 + i) * R + r0 + threadIdx.x] = f2b(v);
    }
}

// bf16 -> bf16 transpose; grid (C/64, R/64), block (64,8)
__global__ __launch_bounds__(512) void transpose_bf16_kernel(
    u16* __restrict__ dst, const u16* __restrict__ src, int R, int C)
{
    __shared__ u16 t[64][65];
    const int c0 = blockIdx.x * 64, r0 = blockIdx.y * 64;
    for (int i = threadIdx.y; i < 64; i += 8)
        t[i][threadIdx.x] = src[(size_t)(r0 + i) * C + c0 + threadIdx.x];
    __syncthreads();
    for (int i = threadIdx.y; i < 64; i += 8)
        dst[(size_t)(c0 + i) * R + r0 + threadIdx.x] = t[threadIdx.x][i];
}

__global__ void ew_softplus_f32(float* __restrict__ dst, const float* __restrict__ src, long n) {
    long i = (long)blockIdx.x * blockDim.x + threadIdx.x;
    const long stride = (long)gridDim.x * blockDim.x;
    for (; i < n; i += stride) dst[i] = softplus_f(src[i]);
}

__global__ void ew_rehu_f32(float* __restrict__ dst, const float* __restrict__ src, long n) {
    long i = (long)blockIdx.x * blockDim.x + threadIdx.x;
    const long stride = (long)gridDim.x * blockDim.x;
    for (; i < n; i += stride) dst[i] = rehu_f(src[i], C_REHU_D);
}

__global__ void clear_kernel(float* __restrict__ dst, long n) {
    long i = (long)blockIdx.x * blockDim.x + threadIdx.x;
    const long stride = (long)gridDim.x * blockDim.x;
    for (; i < n; i += stride) dst[i] = 0.0f;
}

__global__ void fxinit_kernel(float* __restrict__ fxb, const float* __restrict__ fb2p) {
    long i = (long)blockIdx.x * blockDim.x + threadIdx.x;
    const long n = (long)NB * ND;
    const long stride = (long)gridDim.x * blockDim.x;
    for (; i < n; i += stride) fxb[i] = fb2p[i & (ND - 1)];
}

__global__ void fb2p_kernel(float* __restrict__ dst, const float* __restrict__ fb2) {
    const int c = threadIdx.x;
    dst[c] = (c < NOUT) ? fb2[c] : 1.0f;
}

// a2_0[j] = vb1[j] + (1/H) * sum_k z1_0[k] * softplus(vU0[j,k])
__global__ __launch_bounds__(256) void a20_kernel(
    float* __restrict__ a20, const float* __restrict__ z10,
    const float* __restrict__ vU0, const float* __restrict__ vb1)
{
    __shared__ float sbuf[4];
    const int j = blockIdx.x;
    float sum = 0.0f;
    const float* row = vU0 + (size_t)j * NH;
    for (int k = threadIdx.x; k < NH; k += 256) sum += z10[k] * softplus_f(row[k]);
    sum = block_reduce_sum(sum, sbuf);
    if (threadIdx.x == 0) a20[j] = vb1[j] + sum * (1.0f / NH);
}

// icnn0 = vb2 + sum_j rehu(a2_0[j]) * spU1[j]   (vU1.shape[0] == 1 -> no /H)
__global__ __launch_bounds__(256) void icnn0_kernel(
    float* __restrict__ ic0, const float* __restrict__ a20,
    const float* __restrict__ spU1, const float* __restrict__ vb2)
{
    __shared__ float sbuf[4];
    float sum = 0.0f;
    for (int j = threadIdx.x; j < NH; j += 256) sum += rehu_f(a20[j], C_REHU_D) * spU1[j];
    sum = block_reduce_sum(sum, sbuf);
    if (threadIdx.x == 0) ic0[0] = vb2[0] + sum;
}

// per row b: d1 = x.vW2, d2 = ||x||^2; diff = d1 + vb2 + zacc[b] - ic0
// sS = clamp(diff,0,1); sVx = rehu(diff,1) + eps*d2; ga2[b,:] = sS*spU1*drehu(a2)
__global__ __launch_bounds__(256) void rowfin_ga2_kernel(
    float* __restrict__ sS, float* __restrict__ sVx, u16* __restrict__ ga2,
    const float* __restrict__ x, const u16* __restrict__ a2b,
    const float* __restrict__ zacc, const float* __restrict__ spU1,
    const float* __restrict__ vW2, const float* __restrict__ vb2,
    const float* __restrict__ ic0)
{
    __shared__ float sbuf[4];
    __shared__ float ssh;
    const int b = blockIdx.x;
    const int t = threadIdx.x;
    const float xv = x[(size_t)b * ND + t];
    const float d1 = block_reduce_sum(xv * vW2[t], sbuf);
    const float d2 = block_reduce_sum(xv * xv, sbuf);
    if (t == 0) {
        const float diff = d1 + vb2[0] + zacc[b] - ic0[0];
        const float s = fminf(fmaxf(diff / C_PSD_D, 0.0f), 1.0f);
        sS[b]  = s;
        sVx[b] = rehu_f(diff, C_PSD_D) + C_EPS * d2;
        ssh = s;
    }
    __syncthreads();
    const float s = ssh;
    const bf16x8 av = *reinterpret_cast<const bf16x8*>(a2b + (size_t)b * NH + t * 8);
    bf16x8 ov;
    #pragma unroll
    for (int j = 0; j < 8; ++j) {
        const float a2v = b2f((u16)av[j]);
        const float g = s * spU1[t * 8 + j] * drehu_f(a2v, C_REHU_D);
        ov[j] = (short)f2b(g);
    }
    *reinterpret_cast<bf16x8*>(ga2 + (size_t)b * NH + t * 8) = ov;
}

// gV[b,c] = s[b]*vW2[c] + 2*eps*x[b,c]
__global__ void gvinit_kernel(float* __restrict__ gV, const float* __restrict__ sS,
                              const float* __restrict__ vW2, const float* __restrict__ x,
                              long n) {
    long i = (long)blockIdx.x * blockDim.x + threadIdx.x;
    const long stride = (long)gridDim.x * blockDim.x;
    for (; i < n; i += stride) {
        const int b = (int)(i >> 8);
        const int c = (int)(i & (ND - 1));
        gV[i] = sS[b] * vW2[c] + 2.0f * C_EPS * x[i];
    }
}

__global__ __launch_bounds__(256) void final_kernel(
    float* __restrict__ out, const float* __restrict__ gV,
    const float* __restrict__ fx, const float* __restrict__ sVx)
{
    __shared__ float sbuf[4];
    __shared__ float scoef;
    const int b = blockIdx.x;
    const int t = threadIdx.x;
    const float g = gV[(size_t)b * ND + t];
    const float f = fx[(size_t)b * ND + t];
    const float gf = block_reduce_sum(g * f, sbuf);
    const float gg = block_reduce_sum(g * g, sbuf);
    if (t == 0) {
        const float num = fmaxf(gf + C_ALPHA * sVx[b], 0.0f);
        scoef = num / gg;
    }
    __syncthreads();
    const float coef = scoef;
    if (t < NOUT) out[(size_t)b * NOUT + t] = f - g * coef;
}

extern "C" void kernel_launch(void* const* d_in, const int* in_sizes, int n_in,
                              void* d_out, int out_size, void* d_ws, size_t ws_size,
                              hipStream_t stream)
{
    const float* x   = (const float*)d_in[0];
    const float* fW0 = (const float*)d_in[1];
    const float* fb0 = (const float*)d_in[2];
    const float* fW1 = (const float*)d_in[3];
    const float* fb1 = (const float*)d_in[4];
    const float* fW2 = (const float*)d_in[5];
    const float* fb2 = (const float*)d_in[6];
    const float* vW0 = (const float*)d_in[7];
    const float* vb0 = (const float*)d_in[8];
    const float* vW1 = (const float*)d_in[9];
    const float* vb1 = (const float*)d_in[10];
    const float* vW2 = (const float*)d_in[11];
    const float* vb2 = (const float*)d_in[12];
    const float* vU0 = (const float*)d_in[13];
    const float* vU1 = (const float*)d_in[14];
    float* out = (float*)d_out;
    (void)in_sizes; (void)n_in; (void)out_size; (void)d_ws; (void)ws_size;

    u16 *xbf, *buf1, *buf2, *z1b, *a2b, *fW0b, *fW1b, *fW2b, *vW0b, *vW1b, *spU0b, *spU0Tb, *vW0Tb, *vW1Tb;
    float *fxb, *gVb, *fb2p, *spU1, *z10, *a20, *ic0, *zacc, *sS, *sVx;
    hipGetSymbolAddress((void**)&xbf,   HIP_SYMBOL(g_xbf));
    hipGetSymbolAddress((void**)&buf1,  HIP_SYMBOL(g_buf1));
    hipGetSymbolAddress((void**)&buf2,  HIP_SYMBOL(g_buf2));
    hipGetSymbolAddress((void**)&z1b,   HIP_SYMBOL(g_z1));
    hipGetSymbolAddress((void**)&a2b,   HIP_SYMBOL(g_a2b));
    hipGetSymbolAddress((void**)&fxb,   HIP_SYMBOL(g_fxb));
    hipGetSymbolAddress((void**)&gVb,   HIP_SYMBOL(g_gVb));
    hipGetSymbolAddress((void**)&fW0b,  HIP_SYMBOL(g_fW0b));
    hipGetSymbolAddress((void**)&fW1b,  HIP_SYMBOL(g_fW1b));
    hipGetSymbolAddress((void**)&fW2b,  HIP_SYMBOL(g_fW2b));
    hipGetSymbolAddress((void**)&vW0b,  HIP_SYMBOL(g_vW0b));
    hipGetSymbolAddress((void**)&vW1b,  HIP_SYMBOL(g_vW1b));
    hipGetSymbolAddress((void**)&spU0b, HIP_SYMBOL(g_spU0b));
    hipGetSymbolAddress((void**)&spU0Tb,HIP_SYMBOL(g_spU0Tb));
    hipGetSymbolAddress((void**)&vW0Tb, HIP_SYMBOL(g_vW0Tb));
    hipGetSymbolAddress((void**)&vW1Tb, HIP_SYMBOL(g_vW1Tb));
    hipGetSymbolAddress((void**)&fb2p,  HIP_SYMBOL(g_fb2p));
    hipGetSymbolAddress((void**)&spU1,  HIP_SYMBOL(g_spU1));
    hipGetSymbolAddress((void**)&z10,   HIP_SYMBOL(g_z10));
    hipGetSymbolAddress((void**)&a20,   HIP_SYMBOL(g_a20));
    hipGetSymbolAddress((void**)&ic0,   HIP_SYMBOL(g_ic0));
    hipGetSymbolAddress((void**)&zacc,  HIP_SYMBOL(g_zacc));
    hipGetSymbolAddress((void**)&sS,    HIP_SYMBOL(g_sS));
    hipGetSymbolAddress((void**)&sVx,   HIP_SYMBOL(g_sVx));

    // ---- one-time precomputes ----
    cast_kernel<0><<<1024, 256, 0, stream>>>(xbf, x, (long)NB * ND);
    cast_kernel<0><<<512, 256, 0, stream>>>(fW0b, fW0, (long)NH * ND);
    cast_kernel<0><<<2048, 256, 0, stream>>>(fW1b, fW1, (long)NH * NH);
    castpad_kernel<<<512, 256, 0, stream>>>(fW2b, fW2, (long)NOUT * NH, (long)ND * NH);
    cast_kernel<0><<<512, 256, 0, stream>>>(vW0b, vW0, (long)NH * ND);
    cast_kernel<0><<<512, 256, 0, stream>>>(vW1b, vW1, (long)NH * ND);
    cast_kernel<2><<<2048, 256, 0, stream>>>(spU0b, vU0, (long)NH * NH);
    transpose_bf16_kernel<<<dim3(32, 32), dim3(64, 8), 0, stream>>>(spU0Tb, spU0b, NH, NH);
    transpose_cast_kernel<0><<<dim3(8, 64), dim3(32, 8), 0, stream>>>(vW0Tb, vW0, NH, ND);
    transpose_cast_kernel<0><<<dim3(8, 64), dim3(32, 8), 0, stream>>>(vW1Tb, vW1, NH, ND);
    ew_softplus_f32<<<8, 256, 0, stream>>>(spU1, vU1, NH);
    ew_rehu_f32<<<8, 256, 0, stream>>>(z10, vb0, NH);
    fb2p_kernel<<<1, 256, 0, stream>>>(fb2p, fb2);
    a20_kernel<<<NH, 256, 0, stream>>>(a20, z10, vU0, vb1);
    icnn0_kernel<<<1, 256, 0, stream>>>(ic0, a20, spU1, vb2);
    clear_kernel<<<64, 256, 0, stream>>>(zacc, NB);

    // ---- fhat MLP ----
    gemm8<0><<<512, 512, 0, stream>>>(buf1, xbf, ND, fW0b, ND, 4,
        nullptr, 0, nullptr, 0, fb0, nullptr, nullptr, nullptr, NH, 4);
    gemm8<0><<<512, 512, 0, stream>>>(buf2, buf1, NH, fW1b, NH, 32,
        nullptr, 0, nullptr, 0, fb1, nullptr, nullptr, nullptr, NH, 32);
    fxinit_kernel<<<2048, 256, 0, stream>>>(fxb, fb2p);
    mfma_gemm<0><<<dim3(256, 2), 256, 0, stream>>>(fxb, buf2, fW2b, NH, NH,
        nullptr, nullptr, NB, ND, NH / 2);

    // ---- ICNN forward ----
    gemm8<2><<<512, 512, 0, stream>>>(z1b, xbf, ND, vW0b, ND, 4,
        nullptr, 0, nullptr, 0, vb0, nullptr, nullptr, nullptr, NH, 4);
    // a2 = x@vW1^T + vb1 + z1@(spU0/H)^T  (two K-segments) + per-row zacc
    gemm8<3><<<512, 512, 0, stream>>>(a2b, xbf, ND, vW1b, ND, 4,
        z1b, NH, spU0b, NH, vb1, nullptr, zacc, spU1, NH, 36);
    rowfin_ga2_kernel<<<NB, 256, 0, stream>>>(sS, sVx, buf1, x, a2b, zacc, spU1, vW2, vb2, ic0);

    // ---- backward ----
    // g_a1 = (g_a2 @ (spU0/H)) * drehu(a1)  with drehu recovered from z1 bf16
    gemm8<4><<<512, 512, 0, stream>>>(buf2, buf1, NH, spU0Tb, NH, 32,
        nullptr, 0, nullptr, 0, nullptr, z1b, nullptr, nullptr, NH, 32);
    gvinit_kernel<<<2048, 256, 0, stream>>>(gVb, sS, vW2, x, (long)NB * ND);
    // gV += g_a2@vW1T (seg 0) + g_a1@vW0T (seg 1), one launch
    mfma_gemm<1><<<dim3(256, 2), 256, 0, stream>>>(gVb, buf1, vW1Tb, NH, NH,
        buf2, vW0Tb, NB, ND, NH);

    final_kernel<<<NB, 256, 0, stream>>>(out, gVb, fxb, sVx);
}